// Round 10
// baseline (201.600 us; speedup 1.0000x reference)
//
#include <hip/hip_runtime.h>
#include <hip/hip_bf16.h>

#define L_ 2048
#define D_ 192
#define HK_ 48
#define EPS_ 1e-3f
#define SCALE_ 0.28867513459481287f  // 1/sqrt(12)
#define LOG2E_ 1.4426950408889634f

typedef __hip_bfloat16 bf16;
typedef _Float16 f16;
typedef __fp16 hf16x2 __attribute__((ext_vector_type(2)));   // builtin return type
typedef _Float16 f16x4 __attribute__((ext_vector_type(4)));
typedef __bf16 bf16x4 __attribute__((ext_vector_type(4)));
typedef __bf16 bf16x8 __attribute__((ext_vector_type(8)));
typedef float  f32x4  __attribute__((ext_vector_type(4)));

__device__ __forceinline__ float b2f(bf16 x) { return __bfloat162float(x); }
__device__ __forceinline__ bf16 f2b(float x) { return __float2bfloat16(x); }
__device__ __forceinline__ unsigned pk2(float a, float b) {
    union { bf16 h; unsigned short u; } ca, cb;
    ca.h = f2b(a); cb.h = f2b(b);
    return (unsigned)ca.u | ((unsigned)cb.u << 16);
}
__device__ __forceinline__ float uplo(unsigned u) { return __uint_as_float(u << 16); }
__device__ __forceinline__ float uphi(unsigned u) { return __uint_as_float(u & 0xffff0000u); }

// ---------------------------------------------------------------------------
// K0: single prep kernel — all weight repacks in one launch (unchanged).
// ---------------------------------------------------------------------------
__global__ __launch_bounds__(256) void k_prep_all(
    const float* __restrict__ c1w, const float* __restrict__ c2w,
    const float* __restrict__ wq, const float* __restrict__ wk, const float* __restrict__ wv,
    const float* __restrict__ bq, const float* __restrict__ bk, const float* __restrict__ bv,
    const float* __restrict__ wo,
    bf16* __restrict__ wrep1, bf16* __restrict__ wrep2,
    bf16* __restrict__ wrepq, float* __restrict__ bias144, bf16* __restrict__ wrepo)
{
    const int i = blockIdx.x * 256 + threadIdx.x;
    if (i < 110592) {
        const int k = i / 192, n = i - k * 192;
        wrep1[((size_t)(k >> 5) * 192 + n) * 32 + (k & 31)] = f2b(c1w[i]);
    } else if (i < 221184) {
        const int j = i - 110592;
        const int k = j / 192, n = j - k * 192;
        wrep2[((size_t)(k >> 5) * 192 + n) * 32 + (k & 31)] = f2b(c2w[j]);
    } else if (i < 248832) {
        const int j = i - 221184;
        const int kb = j / 4608, rem = j % 4608;
        const int n = rem / 32, kk = rem % 32;
        const int k = kb * 32 + kk;
        float v;
        if (n < 48)       v = wq[k * HK_ + n] * (SCALE_ * LOG2E_);
        else if (n < 96)  v = wk[k * HK_ + (n - 48)];
        else              v = wv[k * HK_ + (n - 96)];
        wrepq[j] = f2b(v);
    } else if (i < 248976) {
        const int j = i - 248832;
        bias144[j] = (j < 48) ? bq[j] * (SCALE_ * LOG2E_)
                   : (j < 96) ? bk[j - 48] : bv[j - 96];
    } else if (i < 261264) {
        const int j = i - 248976;
        const int kb = j / 6144, rem = j % 6144;
        const int n = rem / 32, kk = rem % 32;
        const int k = kb * 32 + kk;
        wrepo[j] = f2b(k < 48 ? wo[k * D_ + n] : 0.f);
    }
}

// ---------------------------------------------------------------------------
// K1: fused LN1 + QKV projection via MFMA (unchanged; q/k head-contiguous
// [b*4+h][2048][12]).
// ---------------------------------------------------------------------------
__global__ __launch_bounds__(256, 4) void k_ln_qkv(
    const float* __restrict__ x, const float* __restrict__ g1, const float* __restrict__ b1,
    const bf16* __restrict__ wrep, const float* __restrict__ bias144,
    f16* __restrict__ qo, f16* __restrict__ ko, f16* __restrict__ vt)
{
    __shared__ bf16 xn[32 * 200];
    const int tid = threadIdx.x;
    const int wave = tid >> 6, lane = tid & 63;
    const int rowbase = blockIdx.x * 32;
    const int b = rowbase >> 11;
    const int lrow0 = rowbase & 2047;

    const float gg0 = g1[lane], gg1 = g1[lane + 64], gg2 = g1[lane + 128];
    const float bb0 = b1[lane], bb1 = b1[lane + 64], bb2 = b1[lane + 128];
    for (int i = 0; i < 8; ++i) {
        const int r = wave * 8 + i;
        const float* xp = x + (size_t)(rowbase + r) * D_;
        const float x0 = xp[lane];
        const float x1 = xp[lane + 64];
        const float x2 = xp[lane + 128];
        float s = x0 + x1 + x2;
        float q = x0 * x0 + x1 * x1 + x2 * x2;
        #pragma unroll
        for (int m = 1; m < 64; m <<= 1) {
            s += __shfl_xor(s, m, 64);
            q += __shfl_xor(q, m, 64);
        }
        const float mean = s * (1.0f / 192.0f);
        const float var  = q * (1.0f / 192.0f) - mean * mean;
        const float rs   = rsqrtf(var + EPS_);
        xn[r * 200 + lane]       = f2b((x0 - mean) * rs * gg0 + bb0);
        xn[r * 200 + lane + 64]  = f2b((x1 - mean) * rs * gg1 + bb1);
        xn[r * 200 + lane + 128] = f2b((x2 - mean) * rs * gg2 + bb2);
    }

    if (tid < 128) {
        const int h  = tid >> 5;
        const int vc = 12 + ((tid >> 3) & 3);
        const int p0 = lrow0 + (tid & 7) * 4;
        f16x4 vv;
        vv[0] = vv[1] = vv[2] = vv[3] = (vc == 12) ? (f16)1.0f : (f16)0.0f;
        *(f16x4*)(vt + ((size_t)(b * 4 + h) * 16 + vc) * 2048 + p0) = vv;
    }
    __syncthreads();

    const int l15 = lane & 15, q4 = lane >> 4;
    const int rt = wave >> 1, g = wave & 1;
    const int ntlim = 5 - g;                 // g=0: nt 0..4, g=1: nt 0..3 (+5)
    f32x4 acc[5];
    #pragma unroll
    for (int nt = 0; nt < 5; ++nt) acc[nt] = (f32x4){0.f, 0.f, 0.f, 0.f};

    const bf16* xrow = xn + (rt * 16 + l15) * 200 + q4 * 8;
    #pragma unroll
    for (int kb = 0; kb < 6; ++kb) {
        const bf16x8 a = *(const bf16x8*)(xrow + kb * 32);
        const bf16* wp = wrep + ((size_t)kb * 144 + l15) * 32 + q4 * 8
                       + (size_t)(g * 5) * 16 * 32;
        #pragma unroll
        for (int nt = 0; nt < 5; ++nt) {
            if (nt < ntlim) {
                const bf16x8 bfr = *(const bf16x8*)(wp + (size_t)nt * 16 * 32);
                acc[nt] = __builtin_amdgcn_mfma_f32_16x16x32_bf16(a, bfr, acc[nt], 0, 0, 0);
            }
        }
    }

    const int lr0 = lrow0 + rt * 16 + q4 * 4;
    #pragma unroll
    for (int nt = 0; nt < 5; ++nt) {
        if (nt < ntlim) {
            const int ntg = g * 5 + nt;
            const int col = ntg * 16 + l15;
            const float bd = bias144[col];
            if (ntg < 3) {
                const int h2 = col / 12, c12 = col - h2 * 12;
                #pragma unroll
                for (int reg = 0; reg < 4; ++reg)
                    qo[((size_t)(b * 4 + h2) * 2048 + lr0 + reg) * 12 + c12] =
                        (f16)(acc[nt][reg] + bd);
            } else if (ntg < 6) {
                const int ck = col - 48;
                const int h2 = ck / 12, c12 = ck - h2 * 12;
                #pragma unroll
                for (int reg = 0; reg < 4; ++reg)
                    ko[((size_t)(b * 4 + h2) * 2048 + lr0 + reg) * 12 + c12] =
                        (f16)(acc[nt][reg] + bd);
            } else {
                const int vcol = col - 96;
                const int h = vcol / 12, c12 = vcol % 12;
                f16x4 vv;
                #pragma unroll
                for (int reg = 0; reg < 4; ++reg) vv[reg] = (f16)(acc[nt][reg] + bd);
                *(f16x4*)(vt + ((size_t)(b * 4 + h) * 16 + c12) * 2048 +
                          lrow0 + rt * 16 + q4 * 4) = vv;
            }
        }
    }
}

// ---------------------------------------------------------------------------
// K2: split-k partials attention. Round-10 change: the k-loop had ZERO
// load/compute overlap (loads, then compute, then next loads). Now a true
// ping-pong double buffer (KA/VA <-> KB/VB, groups of 2 tiles): 4 loads in
// flight under each compute group. +16 VGPR ~= 45 total, inside the 64-reg
// 8-wave tier. ktmax in {4,8,12,16} -> group count even, no loop tail.
// ---------------------------------------------------------------------------
__global__ __launch_bounds__(256, 8) void k_attn_part(
    const f16* __restrict__ qh, const f16* __restrict__ kh, const f16* __restrict__ vt,
    bf16* __restrict__ part_o, float* __restrict__ part_l)
{
    const int tid = threadIdx.x;
    const int wv = tid >> 6, lane = tid & 63;
    const int quad = lane >> 4, l15 = lane & 15;
    const int bh = blockIdx.x / 36;
    int r = blockIdx.x % 36;
    int qt = 0;
    while (r >= qt + 1) { r -= qt + 1; ++qt; }
    const int ks = r;
    const size_t base  = (size_t)bh * 2048 * 12;          // head-contiguous
    const size_t vbase = ((size_t)bh * 16 + l15) * 2048;
    const int kbase = ks * 256;
    const int qbase = qt * 256 + wv * 64;
    const bool diag = (ks == qt);
    const int ktmax = diag ? 4 * (wv + 1) : 16;
    const int ng = ktmax >> 1;               // groups of 2 tiles (even count)

    f16x4 Qf[4];
    #pragma unroll
    for (int s = 0; s < 4; ++s) {
        f16x4 v;
        if (quad < 3)
            v = *(const f16x4*)(qh + base + (size_t)(qbase + s * 16 + l15) * 12 + quad * 4);
        else { v[0] = (f16)LOG2E_; v[1] = 0; v[2] = 0; v[3] = 0; }   // hd12 = log2e
        Qf[s] = v;
    }

    f32x4 O[4];
    #pragma unroll
    for (int s = 0; s < 4; ++s) O[s] = (f32x4){0.f, 0.f, 0.f, 0.f};

    f16x4 KA[2], VA[2], KB[2], VB[2];

    auto LOADG = [&](f16x4* K, f16x4* V, int g) {
        #pragma unroll
        for (int u = 0; u < 2; ++u) {
            const int kt = g * 2 + u;
            if (quad < 3)
                K[u] = *(const f16x4*)(kh + base + (size_t)(kbase + kt * 16 + l15) * 12 + quad * 4);
            else { K[u][0] = (f16)-6.0f; K[u][1] = 0; K[u][2] = 0; K[u][3] = 0; } // hd12 = -6
            V[u] = *(const f16x4*)(vt + vbase + kbase + kt * 16 + quad * 4);
        }
    };
    auto COMPUTE = [&](const f16x4* K, const f16x4* V, int g) {
        #pragma unroll
        for (int u = 0; u < 2; ++u) {
            const int k0 = kbase + (g * 2 + u) * 16 + quad * 4;
            #pragma unroll
            for (int s = 0; s < 4; ++s) {
                f32x4 sc = (f32x4){0.f, 0.f, 0.f, 0.f};
                sc = __builtin_amdgcn_mfma_f32_16x16x16f16(K[u], Qf[s], sc, 0, 0, 0);
                float p0 = __builtin_amdgcn_exp2f(sc[0]);
                float p1 = __builtin_amdgcn_exp2f(sc[1]);
                float p2 = __builtin_amdgcn_exp2f(sc[2]);
                float p3 = __builtin_amdgcn_exp2f(sc[3]);
                if (diag) {
                    const int qg = qbase + s * 16 + l15;
                    p0 = (k0 + 0 <= qg) ? p0 : 0.f;
                    p1 = (k0 + 1 <= qg) ? p1 : 0.f;
                    p2 = (k0 + 2 <= qg) ? p2 : 0.f;
                    p3 = (k0 + 3 <= qg) ? p3 : 0.f;
                }
                const hf16x2 lo = __builtin_amdgcn_cvt_pkrtz(p0, p1);
                const hf16x2 hi = __builtin_amdgcn_cvt_pkrtz(p2, p3);
                f16x4 p;
                p[0] = (f16)lo[0]; p[1] = (f16)lo[1];
                p[2] = (f16)hi[0]; p[3] = (f16)hi[1];
                O[s] = __builtin_amdgcn_mfma_f32_16x16x16f16(p, V[u], O[s], 0, 0, 0);
            }
        }
    };

    LOADG(KA, VA, 0);
    int g = 0;
    while (true) {
        if (g + 1 < ng) LOADG(KB, VB, g + 1);
        COMPUTE(KA, VA, g);
        ++g; if (g >= ng) break;
        if (g + 1 < ng) LOADG(KA, VA, g + 1);
        COMPUTE(KB, VB, g);
        ++g; if (g >= ng) break;
    }

    const size_t pobase = (size_t)(bh * 8 + ks) * 2048;
    #pragma unroll
    for (int s = 0; s < 4; ++s) {
        const int q16 = qbase + s * 16;
        #pragma unroll
        for (int j = 0; j < 4; ++j) {
            const int qq = q16 + quad * 4 + j;
            if (l15 < 12)       part_o[(pobase + qq) * 12 + l15] = f2b(O[s][j]);
            else if (l15 == 12) part_l[pobase + qq] = O[s][j];
        }
    }
}

// ---------------------------------------------------------------------------
// K3: MEGA — combine + out-proj + residual + LN2 + conv1 + conv2 + residual.
// Round-10 changes (r9 lesson: (256,4) = 128 unified arch+acc regs -> the
// allocator SPILLED (WRITE_SIZE +16 MB); unroll-8 combine made it worse):
//  - bounds back to (256,3) — r7-proven no-spill point (WRITE was exactly
//    the 24.6 MB output there). LDS 29.5 KB still allows up to 5 blocks/CU.
//  - vb bf16 packing kept (18 regs saved vs r7).
//  - combine at unroll 4: co-issues 4 independent ~600cy segment loads
//    (halves the A0 serial chain) without r9's pressure blow-up.
// ---------------------------------------------------------------------------
#define CIROWB 400
#define R2OFF  14400              // 36*400 : union { ct[48][72] | h-tile 34 rows }
#define PSOFF  28000              // R2OFF + 34*400
__global__ __launch_bounds__(256, 3) void k_mega(
    const float* __restrict__ x, const bf16* __restrict__ part_o,
    const float* __restrict__ part_l, const bf16* __restrict__ wrepo,
    const float* __restrict__ bo, const float* __restrict__ g2,
    const float* __restrict__ lb2, const bf16* __restrict__ w1,
    const float* __restrict__ b1c, const bf16* __restrict__ w2,
    const float* __restrict__ b2c, float* __restrict__ outf)
{
    __shared__ __align__(16) char lds[29536];
    bf16* ct = (bf16*)(lds + R2OFF);          // [48][72] proj A-tile

    const int tid = threadIdx.x;
    const int wave = tid >> 6, lane = tid & 63;
    const int m16 = lane & 15, q = lane >> 4;
    const int rowbase = blockIdx.x * 32;
    const int b = rowbase >> 11, lrow = rowbase & 2047;
    const int colw = wave * 48;

    // ---- phase A0: combine partials for 36 halo rows (tile rows 0..35) ----
    if (tid < 144) {
        const int rr = tid >> 2, h = tid & 3;
        int qrow = lrow + rr - 2;
        qrow = qrow < 0 ? 0 : (qrow > 2047 ? 2047 : qrow);
        const int nsq = (qrow >> 8) + 1;       // segments valid for this row
        const size_t sb = (size_t)(b * 4 + h) * 8 * 2048 + qrow;
        float o[12];
        #pragma unroll
        for (int i = 0; i < 12; ++i) o[i] = 0.f;
        float l = 0.f;
        #pragma unroll 4
        for (int s = 0; s < 8; ++s) {          // unroll-4: 4 loads co-issue
            if (s < nsq) {
                l += part_l[sb + (size_t)s * 2048];
                const bf16x8 v8 = *(const bf16x8*)(part_o + (sb + (size_t)s * 2048) * 12);
                const bf16x4 v4 = *(const bf16x4*)(part_o + (sb + (size_t)s * 2048) * 12 + 8);
                #pragma unroll
                for (int i = 0; i < 8; ++i) o[i] += (float)v8[i];
                #pragma unroll
                for (int i = 0; i < 4; ++i) o[8 + i] += (float)v4[i];
            }
        }
        const float inv = 1.0f / l;
        bf16* ctp = ct + rr * 72 + h * 12;
        #pragma unroll
        for (int i = 0; i < 12; ++i) ctp[i] = f2b(o[i] * inv);
        bf16x4 z;
        #pragma unroll
        for (int i = 0; i < 4; ++i) z[i] = (__bf16)0.0f;
        *(bf16x4*)(ct + rr * 72 + 48 + h * 4) = z;   // zero K-pad cols 48..63
    } else {
        const int idx = tid - 144;             // zero ct rows 36..47
        if (idx < 108) {
            bf16x8 z;
            #pragma unroll
            for (int i = 0; i < 8; ++i) z[i] = (__bf16)0.0f;
            *(bf16x8*)(ct + 36 * 72 + idx * 8) = z;
        }
    }
    float bd1[3], bd2[3], gg2[3], bbl2[3], bod[3];
    #pragma unroll
    for (int j = 0; j < 3; ++j) {
        const int col = colw + j * 16 + m16;
        bd1[j] = b1c[col]; bd2[j] = b2c[col];
        gg2[j] = g2[col];  bbl2[j] = lb2[col]; bod[j] = bo[col];
    }
    __syncthreads();

    // ---- phase A1: proj MFMA, 3 M-tiles (48 rows, 36 live) x 3 N-tiles ----
    f32x4 pv[3][3];
    #pragma unroll
    for (int mt = 0; mt < 3; ++mt)
        #pragma unroll
        for (int j = 0; j < 3; ++j) pv[mt][j] = (f32x4){0.f, 0.f, 0.f, 0.f};
    #pragma unroll
    for (int kb = 0; kb < 2; ++kb) {
        bf16x8 a[3];
        #pragma unroll
        for (int mt = 0; mt < 3; ++mt)
            a[mt] = *(const bf16x8*)(ct + (mt * 16 + m16) * 72 + kb * 32 + q * 8);
        #pragma unroll
        for (int j = 0; j < 3; ++j) {
            const bf16x8 bb = *(const bf16x8*)(wrepo +
                ((size_t)kb * 192 + (size_t)(wave * 3 + j) * 16 + m16) * 32 + q * 8);
            #pragma unroll
            for (int mt = 0; mt < 3; ++mt)
                pv[mt][j] = __builtin_amdgcn_mfma_f32_16x16x32_bf16(a[mt], bb, pv[mt][j], 0, 0, 0);
        }
    }

    // ---- bias + residual x -> v; per-row sum/ssq (48-col partial per wave) ----
    #pragma unroll
    for (int mt = 0; mt < 3; ++mt) {
        const bool live = (mt < 2) || (q == 0);
        #pragma unroll
        for (int j = 0; j < 3; ++j) {
            const int col = colw + j * 16 + m16;
            #pragma unroll
            for (int reg = 0; reg < 4; ++reg) {
                int grow = lrow + mt * 16 + q * 4 + reg - 2;
                grow = grow < 0 ? 0 : (grow > 2047 ? 2047 : grow);
                float v = 0.f;
                if (live)
                    v = pv[mt][j][reg] + bod[j] + x[((size_t)b * 2048 + grow) * D_ + col];
                pv[mt][j][reg] = v;
            }
        }
    }
    {
        float* ps = (float*)(lds + PSOFF);     // [4][48][2]
        #pragma unroll
        for (int mt = 0; mt < 3; ++mt) {
            float sum[4], ssq[4];
            #pragma unroll
            for (int reg = 0; reg < 4; ++reg) {
                sum[reg] = pv[mt][0][reg] + pv[mt][1][reg] + pv[mt][2][reg];
                ssq[reg] = pv[mt][0][reg] * pv[mt][0][reg]
                         + pv[mt][1][reg] * pv[mt][1][reg]
                         + pv[mt][2][reg] * pv[mt][2][reg];
            }
            #pragma unroll
            for (int m = 1; m <= 8; m <<= 1) {
                #pragma unroll
                for (int reg = 0; reg < 4; ++reg) {
                    sum[reg] += __shfl_xor(sum[reg], m, 64);
                    ssq[reg] += __shfl_xor(ssq[reg], m, 64);
                }
            }
            if (m16 == 0) {
                #pragma unroll
                for (int reg = 0; reg < 4; ++reg) {
                    const int tr = mt * 16 + q * 4 + reg;
                    ps[(wave * 48 + tr) * 2 + 0] = sum[reg];
                    ps[(wave * 48 + tr) * 2 + 1] = ssq[reg];
                }
            }
        }
    }
    __syncthreads();

    // ---- LN2 stats; write xn2 -> conv-input tile; v -> bf16 regs (vb) ----
    unsigned vb[3][3][2];
    {
        const float* ps = (const float*)(lds + PSOFF);
        #pragma unroll
        for (int mt = 0; mt < 3; ++mt) {
            const bool live = (mt < 2) || (q == 0);
            float mean[4], rs[4];
            #pragma unroll
            for (int reg = 0; reg < 4; ++reg) {
                const int tr = mt * 16 + q * 4 + reg;
                float st = 0.f, sq = 0.f;
                #pragma unroll
                for (int w = 0; w < 4; ++w) {
                    st += ps[(w * 48 + tr) * 2 + 0];
                    sq += ps[(w * 48 + tr) * 2 + 1];
                }
                mean[reg] = st * (1.0f / 192.0f);
                const float var = sq * (1.0f / 192.0f) - mean[reg] * mean[reg];
                rs[reg] = rsqrtf(var + EPS_);
            }
            if (live) {
                #pragma unroll
                for (int j = 0; j < 3; ++j) {
                    const int col = colw + j * 16 + m16;
                    #pragma unroll
                    for (int reg = 0; reg < 4; ++reg) {
                        const int tr = mt * 16 + q * 4 + reg;
                        const float v = pv[mt][j][reg];
                        const float xn = (v - mean[reg]) * rs[reg] * gg2[j] + bbl2[j];
                        *(bf16*)(lds + tr * CIROWB + col * 2) = f2b(xn);
                    }
                }
            }
            #pragma unroll
            for (int j = 0; j < 3; ++j) {       // pack v (garbage ok non-live)
                vb[mt][j][0] = pk2(pv[mt][j][0], pv[mt][j][1]);
                vb[mt][j][1] = pk2(pv[mt][j][2], pv[mt][j][3]);
            }
        }
    }
    __syncthreads();

    // ---- phase B: conv1 (3 M-tiles, 34 valid h rows) ----
    const int laneA = m16 * CIROWB + q * 16;
    f32x4 acc1[3][3];
    #pragma unroll
    for (int mt = 0; mt < 3; ++mt)
        #pragma unroll
        for (int j = 0; j < 3; ++j) acc1[mt][j] = (f32x4){0.f, 0.f, 0.f, 0.f};

    #define LOADB(w, kb, j) \
        (*(const bf16x8*)((w) + ((size_t)(kb) * 192 + m16) * 32 + q * 8 \
                          + (size_t)(wave * 3 + (j)) * 16 * 32))
    {
        bf16x8 bB[2][3];
        #pragma unroll
        for (int j = 0; j < 3; ++j) bB[0][j] = LOADB(w1, 0, j);
        #pragma unroll
        for (int kb = 0; kb < 18; ++kb) {
            if (kb + 1 < 18) {
                #pragma unroll
                for (int j = 0; j < 3; ++j) bB[(kb + 1) & 1][j] = LOADB(w1, kb + 1, j);
            }
            const int t = kb / 6, c6 = kb % 6;
            bf16x8 a[3];
            #pragma unroll
            for (int mt = 0; mt < 3; ++mt)
                a[mt] = *(const bf16x8*)(lds + laneA + (mt * 16 + t) * CIROWB + c6 * 64);
            #pragma unroll
            for (int j = 0; j < 3; ++j)
                #pragma unroll
                for (int mt = 0; mt < 3; ++mt)
                    acc1[mt][j] = __builtin_amdgcn_mfma_f32_16x16x32_bf16(
                        a[mt], bB[kb & 1][j], acc1[mt][j], 0, 0, 0);
        }
    }

    // ---- h-tile (relu, edge-zero) -> LDS region2 rows 0..33 ----
    #pragma unroll
    for (int mt = 0; mt < 3; ++mt)
        #pragma unroll
        for (int j = 0; j < 3; ++j)
            #pragma unroll
            for (int reg = 0; reg < 4; ++reg) {
                const int hr = mt * 16 + q * 4 + reg;
                if (hr < 34) {
                    const int hm = lrow + hr - 1;
                    float v = fmaxf(acc1[mt][j][reg] + bd1[j], 0.f);
                    if (hm == 0 || hm == L_ - 1) v = 0.f;
                    *(bf16*)(lds + R2OFF + hr * CIROWB + (colw + j * 16 + m16) * 2) = f2b(v);
                }
            }
    __syncthreads();

    // ---- conv2: 2 M-tiles x 3 N-tiles, A from h-tile ----
    f32x4 acc2[2][3];
    #pragma unroll
    for (int mt = 0; mt < 2; ++mt)
        #pragma unroll
        for (int j = 0; j < 3; ++j) acc2[mt][j] = (f32x4){0.f, 0.f, 0.f, 0.f};
    {
        bf16x8 bB[2][3];
        #pragma unroll
        for (int j = 0; j < 3; ++j) bB[0][j] = LOADB(w2, 0, j);
        #pragma unroll
        for (int kb = 0; kb < 18; ++kb) {
            if (kb + 1 < 18) {
                #pragma unroll
                for (int j = 0; j < 3; ++j) bB[(kb + 1) & 1][j] = LOADB(w2, kb + 1, j);
            }
            const int t = kb / 6, c6 = kb % 6;
            bf16x8 a[2];
            #pragma unroll
            for (int mt = 0; mt < 2; ++mt)
                a[mt] = *(const bf16x8*)(lds + R2OFF + laneA + (mt * 16 + t) * CIROWB + c6 * 64);
            #pragma unroll
            for (int j = 0; j < 3; ++j)
                #pragma unroll
                for (int mt = 0; mt < 2; ++mt)
                    acc2[mt][j] = __builtin_amdgcn_mfma_f32_16x16x32_bf16(
                        a[mt], bB[kb & 1][j], acc2[mt][j], 0, 0, 0);
        }
    }
    #undef LOADB

    // ---- epilogue: residual v from vb regs (row shift +2 via shfl) + conv2 ----
    const int lsrc = (lane + 16) & 63;
    #pragma unroll
    for (int mt = 0; mt < 2; ++mt)
        #pragma unroll
        for (int j = 0; j < 3; ++j) {
            // provider-side select: q==0 lanes supply vb[mt+1] (consumer q==3)
            const unsigned s01 = (q == 0) ? vb[mt + 1][j][0] : vb[mt][j][0];
            const unsigned o01 = (unsigned)__shfl((int)s01, lsrc, 64);
            const unsigned own23 = vb[mt][j][1];
            const float vv0 = uplo(own23), vv1 = uphi(own23);
            const float v2 = uplo(o01),  v3 = uphi(o01);
            const int col = colw + j * 16 + m16;
            #pragma unroll
            for (int reg = 0; reg < 4; ++reg) {
                const int r = rowbase + mt * 16 + q * 4 + reg;
                const int m = r & (L_ - 1);
                float v = (reg == 0) ? vv0 : (reg == 1) ? vv1 : (reg == 2) ? v2 : v3;
                if (m != 0 && m != L_ - 1) v += acc2[mt][j][reg] + bd2[j];
                outf[(size_t)r * D_ + col] = v;
            }
        }
}

// ---------------------------------------------------------------------------
extern "C" void kernel_launch(void* const* d_in, const int* in_sizes, int n_in,
                              void* d_out, int out_size, void* d_ws, size_t ws_size,
                              hipStream_t stream)
{
    const float* x    = (const float*)d_in[0];
    const float* ln1g = (const float*)d_in[1];
    const float* ln1b = (const float*)d_in[2];
    const float* wq   = (const float*)d_in[3];
    const float* bq   = (const float*)d_in[4];
    const float* wk   = (const float*)d_in[5];
    const float* bk   = (const float*)d_in[6];
    const float* wv   = (const float*)d_in[7];
    const float* bv   = (const float*)d_in[8];
    const float* wo   = (const float*)d_in[9];
    const float* bo   = (const float*)d_in[10];
    const float* ln2g = (const float*)d_in[11];
    const float* ln2b = (const float*)d_in[12];
    const float* c1w  = (const float*)d_in[13];
    const float* c1b  = (const float*)d_in[14];
    const float* c2w  = (const float*)d_in[15];
    const float* c2b  = (const float*)d_in[16];

    const size_t ROWS = (size_t)16 * L_;            // 32768
    char* ws = (char*)d_ws;
    size_t off = 0;
    f16* qb    = (f16*)(ws + off);   off += ROWS * HK_ * 2;  // 3.15 MB
    f16* kb    = (f16*)(ws + off);   off += ROWS * HK_ * 2;
    f16* vt    = (f16*)(ws + off);   off += (size_t)64 * 16 * 2048 * 2;   // 4.19 MB
    bf16* part_o = (bf16*)(ws + off); off += (size_t)64 * 8 * 2048 * 12 * 2; // 25.2 MB
    float* part_l = (float*)(ws + off); off += (size_t)64 * 8 * 2048 * 4;    //  4.2 MB
    bf16* wrep1 = (bf16*)(ws + off); off += 576 * 192 * 2;   // 221 KB
    bf16* wrep2 = (bf16*)(ws + off); off += 576 * 192 * 2;
    bf16* wrepq = (bf16*)(ws + off); off += 6 * 144 * 32 * 2;
    float* bias144 = (float*)(ws + off); off += 144 * 4;
    bf16* wrepo = (bf16*)(ws + off); off += 2 * 192 * 32 * 2; // total ~37 MB

    k_prep_all  <<<1021, 256, 0, stream>>>(c1w, c2w, wq, wk, wv, bq, bk, bv, wo,
                                           wrep1, wrep2, wrepq, bias144, wrepo);
    k_ln_qkv    <<<1024, 256, 0, stream>>>(x, ln1g, ln1b, wrepq, bias144, qb, kb, vt);
    k_attn_part <<<64 * 36, 256, 0, stream>>>(qb, kb, vt, part_o, part_l);
    k_mega      <<<1024, 256, 0, stream>>>(x, part_o, part_l, wrepo, bo, ln2g, ln2b,
                                           wrep1, c1b, wrep2, c2b, (float*)d_out);
}

// Round 11
// 199.158 us; speedup vs baseline: 1.0123x; 1.0123x over previous
//
#include <hip/hip_runtime.h>
#include <hip/hip_bf16.h>

#define L_ 2048
#define D_ 192
#define HK_ 48
#define EPS_ 1e-3f
#define SCALE_ 0.28867513459481287f  // 1/sqrt(12)
#define LOG2E_ 1.4426950408889634f

typedef __hip_bfloat16 bf16;
typedef _Float16 f16;
typedef __fp16 hf16x2 __attribute__((ext_vector_type(2)));   // builtin return type
typedef _Float16 f16x4 __attribute__((ext_vector_type(4)));
typedef __bf16 bf16x4 __attribute__((ext_vector_type(4)));
typedef __bf16 bf16x8 __attribute__((ext_vector_type(8)));
typedef float  f32x4  __attribute__((ext_vector_type(4)));

__device__ __forceinline__ float b2f(bf16 x) { return __bfloat162float(x); }
__device__ __forceinline__ bf16 f2b(float x) { return __float2bfloat16(x); }
__device__ __forceinline__ unsigned pk2(float a, float b) {
    union { bf16 h; unsigned short u; } ca, cb;
    ca.h = f2b(a); cb.h = f2b(b);
    return (unsigned)ca.u | ((unsigned)cb.u << 16);
}
__device__ __forceinline__ float uplo(unsigned u) { return __uint_as_float(u << 16); }
__device__ __forceinline__ float uphi(unsigned u) { return __uint_as_float(u & 0xffff0000u); }

// ---------------------------------------------------------------------------
// K0: single prep kernel — all weight repacks in one launch (unchanged).
// ---------------------------------------------------------------------------
__global__ __launch_bounds__(256) void k_prep_all(
    const float* __restrict__ c1w, const float* __restrict__ c2w,
    const float* __restrict__ wq, const float* __restrict__ wk, const float* __restrict__ wv,
    const float* __restrict__ bq, const float* __restrict__ bk, const float* __restrict__ bv,
    const float* __restrict__ wo,
    bf16* __restrict__ wrep1, bf16* __restrict__ wrep2,
    bf16* __restrict__ wrepq, float* __restrict__ bias144, bf16* __restrict__ wrepo)
{
    const int i = blockIdx.x * 256 + threadIdx.x;
    if (i < 110592) {
        const int k = i / 192, n = i - k * 192;
        wrep1[((size_t)(k >> 5) * 192 + n) * 32 + (k & 31)] = f2b(c1w[i]);
    } else if (i < 221184) {
        const int j = i - 110592;
        const int k = j / 192, n = j - k * 192;
        wrep2[((size_t)(k >> 5) * 192 + n) * 32 + (k & 31)] = f2b(c2w[j]);
    } else if (i < 248832) {
        const int j = i - 221184;
        const int kb = j / 4608, rem = j % 4608;
        const int n = rem / 32, kk = rem % 32;
        const int k = kb * 32 + kk;
        float v;
        if (n < 48)       v = wq[k * HK_ + n] * (SCALE_ * LOG2E_);
        else if (n < 96)  v = wk[k * HK_ + (n - 48)];
        else              v = wv[k * HK_ + (n - 96)];
        wrepq[j] = f2b(v);
    } else if (i < 248976) {
        const int j = i - 248832;
        bias144[j] = (j < 48) ? bq[j] * (SCALE_ * LOG2E_)
                   : (j < 96) ? bk[j - 48] : bv[j - 96];
    } else if (i < 261264) {
        const int j = i - 248976;
        const int kb = j / 6144, rem = j % 6144;
        const int n = rem / 32, kk = rem % 32;
        const int k = kb * 32 + kk;
        wrepo[j] = f2b(k < 48 ? wo[k * D_ + n] : 0.f);
    }
}

// ---------------------------------------------------------------------------
// K1: fused LN1 + QKV projection via MFMA (unchanged; q/k head-contiguous
// [b*4+h][2048][12]).
// ---------------------------------------------------------------------------
__global__ __launch_bounds__(256, 4) void k_ln_qkv(
    const float* __restrict__ x, const float* __restrict__ g1, const float* __restrict__ b1,
    const bf16* __restrict__ wrep, const float* __restrict__ bias144,
    f16* __restrict__ qo, f16* __restrict__ ko, f16* __restrict__ vt)
{
    __shared__ bf16 xn[32 * 200];
    const int tid = threadIdx.x;
    const int wave = tid >> 6, lane = tid & 63;
    const int rowbase = blockIdx.x * 32;
    const int b = rowbase >> 11;
    const int lrow0 = rowbase & 2047;

    const float gg0 = g1[lane], gg1 = g1[lane + 64], gg2 = g1[lane + 128];
    const float bb0 = b1[lane], bb1 = b1[lane + 64], bb2 = b1[lane + 128];
    for (int i = 0; i < 8; ++i) {
        const int r = wave * 8 + i;
        const float* xp = x + (size_t)(rowbase + r) * D_;
        const float x0 = xp[lane];
        const float x1 = xp[lane + 64];
        const float x2 = xp[lane + 128];
        float s = x0 + x1 + x2;
        float q = x0 * x0 + x1 * x1 + x2 * x2;
        #pragma unroll
        for (int m = 1; m < 64; m <<= 1) {
            s += __shfl_xor(s, m, 64);
            q += __shfl_xor(q, m, 64);
        }
        const float mean = s * (1.0f / 192.0f);
        const float var  = q * (1.0f / 192.0f) - mean * mean;
        const float rs   = rsqrtf(var + EPS_);
        xn[r * 200 + lane]       = f2b((x0 - mean) * rs * gg0 + bb0);
        xn[r * 200 + lane + 64]  = f2b((x1 - mean) * rs * gg1 + bb1);
        xn[r * 200 + lane + 128] = f2b((x2 - mean) * rs * gg2 + bb2);
    }

    if (tid < 128) {
        const int h  = tid >> 5;
        const int vc = 12 + ((tid >> 3) & 3);
        const int p0 = lrow0 + (tid & 7) * 4;
        f16x4 vv;
        vv[0] = vv[1] = vv[2] = vv[3] = (vc == 12) ? (f16)1.0f : (f16)0.0f;
        *(f16x4*)(vt + ((size_t)(b * 4 + h) * 16 + vc) * 2048 + p0) = vv;
    }
    __syncthreads();

    const int l15 = lane & 15, q4 = lane >> 4;
    const int rt = wave >> 1, g = wave & 1;
    const int ntlim = 5 - g;                 // g=0: nt 0..4, g=1: nt 0..3 (+5)
    f32x4 acc[5];
    #pragma unroll
    for (int nt = 0; nt < 5; ++nt) acc[nt] = (f32x4){0.f, 0.f, 0.f, 0.f};

    const bf16* xrow = xn + (rt * 16 + l15) * 200 + q4 * 8;
    #pragma unroll
    for (int kb = 0; kb < 6; ++kb) {
        const bf16x8 a = *(const bf16x8*)(xrow + kb * 32);
        const bf16* wp = wrep + ((size_t)kb * 144 + l15) * 32 + q4 * 8
                       + (size_t)(g * 5) * 16 * 32;
        #pragma unroll
        for (int nt = 0; nt < 5; ++nt) {
            if (nt < ntlim) {
                const bf16x8 bfr = *(const bf16x8*)(wp + (size_t)nt * 16 * 32);
                acc[nt] = __builtin_amdgcn_mfma_f32_16x16x32_bf16(a, bfr, acc[nt], 0, 0, 0);
            }
        }
    }

    const int lr0 = lrow0 + rt * 16 + q4 * 4;
    #pragma unroll
    for (int nt = 0; nt < 5; ++nt) {
        if (nt < ntlim) {
            const int ntg = g * 5 + nt;
            const int col = ntg * 16 + l15;
            const float bd = bias144[col];
            if (ntg < 3) {
                const int h2 = col / 12, c12 = col - h2 * 12;
                #pragma unroll
                for (int reg = 0; reg < 4; ++reg)
                    qo[((size_t)(b * 4 + h2) * 2048 + lr0 + reg) * 12 + c12] =
                        (f16)(acc[nt][reg] + bd);
            } else if (ntg < 6) {
                const int ck = col - 48;
                const int h2 = ck / 12, c12 = ck - h2 * 12;
                #pragma unroll
                for (int reg = 0; reg < 4; ++reg)
                    ko[((size_t)(b * 4 + h2) * 2048 + lr0 + reg) * 12 + c12] =
                        (f16)(acc[nt][reg] + bd);
            } else {
                const int vcol = col - 96;
                const int h = vcol / 12, c12 = vcol % 12;
                f16x4 vv;
                #pragma unroll
                for (int reg = 0; reg < 4; ++reg) vv[reg] = (f16)(acc[nt][reg] + bd);
                *(f16x4*)(vt + ((size_t)(b * 4 + h) * 16 + c12) * 2048 +
                          lrow0 + rt * 16 + q4 * 4) = vv;
            }
        }
    }
}

// ---------------------------------------------------------------------------
// K2: split-k partials attention — REVERTED to the r7-proven simple loop
// (r10's lambda ping-pong regressed ~5 µs; same failure mode as round 6:
// restructured loops perturb the compiler's schedule).
// ---------------------------------------------------------------------------
__global__ __launch_bounds__(256, 8) void k_attn_part(
    const f16* __restrict__ qh, const f16* __restrict__ kh, const f16* __restrict__ vt,
    bf16* __restrict__ part_o, float* __restrict__ part_l)
{
    const int tid = threadIdx.x;
    const int wv = tid >> 6, lane = tid & 63;
    const int quad = lane >> 4, l15 = lane & 15;
    const int bh = blockIdx.x / 36;
    int r = blockIdx.x % 36;
    int qt = 0;
    while (r >= qt + 1) { r -= qt + 1; ++qt; }
    const int ks = r;
    const size_t base  = (size_t)bh * 2048 * 12;          // head-contiguous
    const size_t vbase = ((size_t)bh * 16 + l15) * 2048;
    const int kbase = ks * 256;
    const int qbase = qt * 256 + wv * 64;
    const bool diag = (ks == qt);
    const int ktmax = diag ? 4 * (wv + 1) : 16;

    f16x4 Qf[4];
    #pragma unroll
    for (int s = 0; s < 4; ++s) {
        f16x4 v;
        if (quad < 3)
            v = *(const f16x4*)(qh + base + (size_t)(qbase + s * 16 + l15) * 12 + quad * 4);
        else { v[0] = (f16)LOG2E_; v[1] = 0; v[2] = 0; v[3] = 0; }   // hd12 = log2e
        Qf[s] = v;
    }

    f32x4 O[4];
    #pragma unroll
    for (int s = 0; s < 4; ++s) O[s] = (f32x4){0.f, 0.f, 0.f, 0.f};

    for (int g = 0; g < ktmax; g += 2) {
        f16x4 Kg[2], Vg[2];
        #pragma unroll
        for (int u = 0; u < 2; ++u) {
            const int kt = g + u;
            f16x4 kf;
            if (quad < 3)
                kf = *(const f16x4*)(kh + base + (size_t)(kbase + kt * 16 + l15) * 12 + quad * 4);
            else { kf[0] = (f16)-6.0f; kf[1] = 0; kf[2] = 0; kf[3] = 0; } // hd12 = -6
            Kg[u] = kf;
            Vg[u] = *(const f16x4*)(vt + vbase + kbase + kt * 16 + quad * 4);
        }
        #pragma unroll
        for (int u = 0; u < 2; ++u) {
            const int k0 = kbase + (g + u) * 16 + quad * 4;
            #pragma unroll
            for (int s = 0; s < 4; ++s) {
                f32x4 sc = (f32x4){0.f, 0.f, 0.f, 0.f};
                sc = __builtin_amdgcn_mfma_f32_16x16x16f16(Kg[u], Qf[s], sc, 0, 0, 0);
                float p0 = __builtin_amdgcn_exp2f(sc[0]);
                float p1 = __builtin_amdgcn_exp2f(sc[1]);
                float p2 = __builtin_amdgcn_exp2f(sc[2]);
                float p3 = __builtin_amdgcn_exp2f(sc[3]);
                if (diag) {
                    const int qg = qbase + s * 16 + l15;
                    p0 = (k0 + 0 <= qg) ? p0 : 0.f;
                    p1 = (k0 + 1 <= qg) ? p1 : 0.f;
                    p2 = (k0 + 2 <= qg) ? p2 : 0.f;
                    p3 = (k0 + 3 <= qg) ? p3 : 0.f;
                }
                const hf16x2 lo = __builtin_amdgcn_cvt_pkrtz(p0, p1);
                const hf16x2 hi = __builtin_amdgcn_cvt_pkrtz(p2, p3);
                f16x4 p;
                p[0] = (f16)lo[0]; p[1] = (f16)lo[1];
                p[2] = (f16)hi[0]; p[3] = (f16)hi[1];
                O[s] = __builtin_amdgcn_mfma_f32_16x16x16f16(p, Vg[u], O[s], 0, 0, 0);
            }
        }
    }

    const size_t pobase = (size_t)(bh * 8 + ks) * 2048;
    #pragma unroll
    for (int s = 0; s < 4; ++s) {
        const int q16 = qbase + s * 16;
        #pragma unroll
        for (int j = 0; j < 4; ++j) {
            const int qq = q16 + quad * 4 + j;
            if (l15 < 12)       part_o[(pobase + qq) * 12 + l15] = f2b(O[s][j]);
            else if (l15 == 12) part_l[pobase + qq] = O[s][j];
        }
    }
}

// ---------------------------------------------------------------------------
// K3: MEGA — combine + out-proj + residual + LN2 + conv1 + conv2 + residual.
// Round-11 change: r10 measured natural VGPR usage = 84 at the (256,3)
// budget with NO spill (WRITE_SIZE = exactly the 24.6 MB output). 84 fits
// the (256,4) 128-reg budget, and LDS is 29.5 KB (5 blocks/CU by LDS) — so
// take the 4-blocks/CU occupancy r8 wanted, this time without r8's spill
// (pv is vb-packed) and without r9's unroll-8 pressure blow-up (unroll 4).
// ---------------------------------------------------------------------------
#define CIROWB 400
#define R2OFF  14400              // 36*400 : union { ct[48][72] | h-tile 34 rows }
#define PSOFF  28000              // R2OFF + 34*400
__global__ __launch_bounds__(256, 4) void k_mega(
    const float* __restrict__ x, const bf16* __restrict__ part_o,
    const float* __restrict__ part_l, const bf16* __restrict__ wrepo,
    const float* __restrict__ bo, const float* __restrict__ g2,
    const float* __restrict__ lb2, const bf16* __restrict__ w1,
    const float* __restrict__ b1c, const bf16* __restrict__ w2,
    const float* __restrict__ b2c, float* __restrict__ outf)
{
    __shared__ __align__(16) char lds[29536];
    bf16* ct = (bf16*)(lds + R2OFF);          // [48][72] proj A-tile

    const int tid = threadIdx.x;
    const int wave = tid >> 6, lane = tid & 63;
    const int m16 = lane & 15, q = lane >> 4;
    const int rowbase = blockIdx.x * 32;
    const int b = rowbase >> 11, lrow = rowbase & 2047;
    const int colw = wave * 48;

    // ---- phase A0: combine partials for 36 halo rows (tile rows 0..35) ----
    if (tid < 144) {
        const int rr = tid >> 2, h = tid & 3;
        int qrow = lrow + rr - 2;
        qrow = qrow < 0 ? 0 : (qrow > 2047 ? 2047 : qrow);
        const int nsq = (qrow >> 8) + 1;       // segments valid for this row
        const size_t sb = (size_t)(b * 4 + h) * 8 * 2048 + qrow;
        float o[12];
        #pragma unroll
        for (int i = 0; i < 12; ++i) o[i] = 0.f;
        float l = 0.f;
        #pragma unroll 4
        for (int s = 0; s < 8; ++s) {          // unroll-4: 4 loads co-issue
            if (s < nsq) {
                l += part_l[sb + (size_t)s * 2048];
                const bf16x8 v8 = *(const bf16x8*)(part_o + (sb + (size_t)s * 2048) * 12);
                const bf16x4 v4 = *(const bf16x4*)(part_o + (sb + (size_t)s * 2048) * 12 + 8);
                #pragma unroll
                for (int i = 0; i < 8; ++i) o[i] += (float)v8[i];
                #pragma unroll
                for (int i = 0; i < 4; ++i) o[8 + i] += (float)v4[i];
            }
        }
        const float inv = 1.0f / l;
        bf16* ctp = ct + rr * 72 + h * 12;
        #pragma unroll
        for (int i = 0; i < 12; ++i) ctp[i] = f2b(o[i] * inv);
        bf16x4 z;
        #pragma unroll
        for (int i = 0; i < 4; ++i) z[i] = (__bf16)0.0f;
        *(bf16x4*)(ct + rr * 72 + 48 + h * 4) = z;   // zero K-pad cols 48..63
    } else {
        const int idx = tid - 144;             // zero ct rows 36..47
        if (idx < 108) {
            bf16x8 z;
            #pragma unroll
            for (int i = 0; i < 8; ++i) z[i] = (__bf16)0.0f;
            *(bf16x8*)(ct + 36 * 72 + idx * 8) = z;
        }
    }
    float bd1[3], bd2[3], gg2[3], bbl2[3], bod[3];
    #pragma unroll
    for (int j = 0; j < 3; ++j) {
        const int col = colw + j * 16 + m16;
        bd1[j] = b1c[col]; bd2[j] = b2c[col];
        gg2[j] = g2[col];  bbl2[j] = lb2[col]; bod[j] = bo[col];
    }
    __syncthreads();

    // ---- phase A1: proj MFMA, 3 M-tiles (48 rows, 36 live) x 3 N-tiles ----
    f32x4 pv[3][3];
    #pragma unroll
    for (int mt = 0; mt < 3; ++mt)
        #pragma unroll
        for (int j = 0; j < 3; ++j) pv[mt][j] = (f32x4){0.f, 0.f, 0.f, 0.f};
    #pragma unroll
    for (int kb = 0; kb < 2; ++kb) {
        bf16x8 a[3];
        #pragma unroll
        for (int mt = 0; mt < 3; ++mt)
            a[mt] = *(const bf16x8*)(ct + (mt * 16 + m16) * 72 + kb * 32 + q * 8);
        #pragma unroll
        for (int j = 0; j < 3; ++j) {
            const bf16x8 bb = *(const bf16x8*)(wrepo +
                ((size_t)kb * 192 + (size_t)(wave * 3 + j) * 16 + m16) * 32 + q * 8);
            #pragma unroll
            for (int mt = 0; mt < 3; ++mt)
                pv[mt][j] = __builtin_amdgcn_mfma_f32_16x16x32_bf16(a[mt], bb, pv[mt][j], 0, 0, 0);
        }
    }

    // ---- bias + residual x -> v; per-row sum/ssq (48-col partial per wave) ----
    #pragma unroll
    for (int mt = 0; mt < 3; ++mt) {
        const bool live = (mt < 2) || (q == 0);
        #pragma unroll
        for (int j = 0; j < 3; ++j) {
            const int col = colw + j * 16 + m16;
            #pragma unroll
            for (int reg = 0; reg < 4; ++reg) {
                int grow = lrow + mt * 16 + q * 4 + reg - 2;
                grow = grow < 0 ? 0 : (grow > 2047 ? 2047 : grow);
                float v = 0.f;
                if (live)
                    v = pv[mt][j][reg] + bod[j] + x[((size_t)b * 2048 + grow) * D_ + col];
                pv[mt][j][reg] = v;
            }
        }
    }
    {
        float* ps = (float*)(lds + PSOFF);     // [4][48][2]
        #pragma unroll
        for (int mt = 0; mt < 3; ++mt) {
            float sum[4], ssq[4];
            #pragma unroll
            for (int reg = 0; reg < 4; ++reg) {
                sum[reg] = pv[mt][0][reg] + pv[mt][1][reg] + pv[mt][2][reg];
                ssq[reg] = pv[mt][0][reg] * pv[mt][0][reg]
                         + pv[mt][1][reg] * pv[mt][1][reg]
                         + pv[mt][2][reg] * pv[mt][2][reg];
            }
            #pragma unroll
            for (int m = 1; m <= 8; m <<= 1) {
                #pragma unroll
                for (int reg = 0; reg < 4; ++reg) {
                    sum[reg] += __shfl_xor(sum[reg], m, 64);
                    ssq[reg] += __shfl_xor(ssq[reg], m, 64);
                }
            }
            if (m16 == 0) {
                #pragma unroll
                for (int reg = 0; reg < 4; ++reg) {
                    const int tr = mt * 16 + q * 4 + reg;
                    ps[(wave * 48 + tr) * 2 + 0] = sum[reg];
                    ps[(wave * 48 + tr) * 2 + 1] = ssq[reg];
                }
            }
        }
    }
    __syncthreads();

    // ---- LN2 stats; write xn2 -> conv-input tile; v -> bf16 regs (vb) ----
    unsigned vb[3][3][2];
    {
        const float* ps = (const float*)(lds + PSOFF);
        #pragma unroll
        for (int mt = 0; mt < 3; ++mt) {
            const bool live = (mt < 2) || (q == 0);
            float mean[4], rs[4];
            #pragma unroll
            for (int reg = 0; reg < 4; ++reg) {
                const int tr = mt * 16 + q * 4 + reg;
                float st = 0.f, sq = 0.f;
                #pragma unroll
                for (int w = 0; w < 4; ++w) {
                    st += ps[(w * 48 + tr) * 2 + 0];
                    sq += ps[(w * 48 + tr) * 2 + 1];
                }
                mean[reg] = st * (1.0f / 192.0f);
                const float var = sq * (1.0f / 192.0f) - mean[reg] * mean[reg];
                rs[reg] = rsqrtf(var + EPS_);
            }
            if (live) {
                #pragma unroll
                for (int j = 0; j < 3; ++j) {
                    const int col = colw + j * 16 + m16;
                    #pragma unroll
                    for (int reg = 0; reg < 4; ++reg) {
                        const int tr = mt * 16 + q * 4 + reg;
                        const float v = pv[mt][j][reg];
                        const float xn = (v - mean[reg]) * rs[reg] * gg2[j] + bbl2[j];
                        *(bf16*)(lds + tr * CIROWB + col * 2) = f2b(xn);
                    }
                }
            }
            #pragma unroll
            for (int j = 0; j < 3; ++j) {       // pack v (garbage ok non-live)
                vb[mt][j][0] = pk2(pv[mt][j][0], pv[mt][j][1]);
                vb[mt][j][1] = pk2(pv[mt][j][2], pv[mt][j][3]);
            }
        }
    }
    __syncthreads();

    // ---- phase B: conv1 (3 M-tiles, 34 valid h rows) ----
    const int laneA = m16 * CIROWB + q * 16;
    f32x4 acc1[3][3];
    #pragma unroll
    for (int mt = 0; mt < 3; ++mt)
        #pragma unroll
        for (int j = 0; j < 3; ++j) acc1[mt][j] = (f32x4){0.f, 0.f, 0.f, 0.f};

    #define LOADB(w, kb, j) \
        (*(const bf16x8*)((w) + ((size_t)(kb) * 192 + m16) * 32 + q * 8 \
                          + (size_t)(wave * 3 + (j)) * 16 * 32))
    {
        bf16x8 bB[2][3];
        #pragma unroll
        for (int j = 0; j < 3; ++j) bB[0][j] = LOADB(w1, 0, j);
        #pragma unroll
        for (int kb = 0; kb < 18; ++kb) {
            if (kb + 1 < 18) {
                #pragma unroll
                for (int j = 0; j < 3; ++j) bB[(kb + 1) & 1][j] = LOADB(w1, kb + 1, j);
            }
            const int t = kb / 6, c6 = kb % 6;
            bf16x8 a[3];
            #pragma unroll
            for (int mt = 0; mt < 3; ++mt)
                a[mt] = *(const bf16x8*)(lds + laneA + (mt * 16 + t) * CIROWB + c6 * 64);
            #pragma unroll
            for (int j = 0; j < 3; ++j)
                #pragma unroll
                for (int mt = 0; mt < 3; ++mt)
                    acc1[mt][j] = __builtin_amdgcn_mfma_f32_16x16x32_bf16(
                        a[mt], bB[kb & 1][j], acc1[mt][j], 0, 0, 0);
        }
    }

    // ---- h-tile (relu, edge-zero) -> LDS region2 rows 0..33 ----
    #pragma unroll
    for (int mt = 0; mt < 3; ++mt)
        #pragma unroll
        for (int j = 0; j < 3; ++j)
            #pragma unroll
            for (int reg = 0; reg < 4; ++reg) {
                const int hr = mt * 16 + q * 4 + reg;
                if (hr < 34) {
                    const int hm = lrow + hr - 1;
                    float v = fmaxf(acc1[mt][j][reg] + bd1[j], 0.f);
                    if (hm == 0 || hm == L_ - 1) v = 0.f;
                    *(bf16*)(lds + R2OFF + hr * CIROWB + (colw + j * 16 + m16) * 2) = f2b(v);
                }
            }
    __syncthreads();

    // ---- conv2: 2 M-tiles x 3 N-tiles, A from h-tile ----
    f32x4 acc2[2][3];
    #pragma unroll
    for (int mt = 0; mt < 2; ++mt)
        #pragma unroll
        for (int j = 0; j < 3; ++j) acc2[mt][j] = (f32x4){0.f, 0.f, 0.f, 0.f};
    {
        bf16x8 bB[2][3];
        #pragma unroll
        for (int j = 0; j < 3; ++j) bB[0][j] = LOADB(w2, 0, j);
        #pragma unroll
        for (int kb = 0; kb < 18; ++kb) {
            if (kb + 1 < 18) {
                #pragma unroll
                for (int j = 0; j < 3; ++j) bB[(kb + 1) & 1][j] = LOADB(w2, kb + 1, j);
            }
            const int t = kb / 6, c6 = kb % 6;
            bf16x8 a[2];
            #pragma unroll
            for (int mt = 0; mt < 2; ++mt)
                a[mt] = *(const bf16x8*)(lds + R2OFF + laneA + (mt * 16 + t) * CIROWB + c6 * 64);
            #pragma unroll
            for (int j = 0; j < 3; ++j)
                #pragma unroll
                for (int mt = 0; mt < 2; ++mt)
                    acc2[mt][j] = __builtin_amdgcn_mfma_f32_16x16x32_bf16(
                        a[mt], bB[kb & 1][j], acc2[mt][j], 0, 0, 0);
        }
    }
    #undef LOADB

    // ---- epilogue: residual v from vb regs (row shift +2 via shfl) + conv2 ----
    const int lsrc = (lane + 16) & 63;
    #pragma unroll
    for (int mt = 0; mt < 2; ++mt)
        #pragma unroll
        for (int j = 0; j < 3; ++j) {
            // provider-side select: q==0 lanes supply vb[mt+1] (consumer q==3)
            const unsigned s01 = (q == 0) ? vb[mt + 1][j][0] : vb[mt][j][0];
            const unsigned o01 = (unsigned)__shfl((int)s01, lsrc, 64);
            const unsigned own23 = vb[mt][j][1];
            const float vv0 = uplo(own23), vv1 = uphi(own23);
            const float v2 = uplo(o01),  v3 = uphi(o01);
            const int col = colw + j * 16 + m16;
            #pragma unroll
            for (int reg = 0; reg < 4; ++reg) {
                const int r = rowbase + mt * 16 + q * 4 + reg;
                const int m = r & (L_ - 1);
                float v = (reg == 0) ? vv0 : (reg == 1) ? vv1 : (reg == 2) ? v2 : v3;
                if (m != 0 && m != L_ - 1) v += acc2[mt][j][reg] + bd2[j];
                outf[(size_t)r * D_ + col] = v;
            }
        }
}

// ---------------------------------------------------------------------------
extern "C" void kernel_launch(void* const* d_in, const int* in_sizes, int n_in,
                              void* d_out, int out_size, void* d_ws, size_t ws_size,
                              hipStream_t stream)
{
    const float* x    = (const float*)d_in[0];
    const float* ln1g = (const float*)d_in[1];
    const float* ln1b = (const float*)d_in[2];
    const float* wq   = (const float*)d_in[3];
    const float* bq   = (const float*)d_in[4];
    const float* wk   = (const float*)d_in[5];
    const float* bk   = (const float*)d_in[6];
    const float* wv   = (const float*)d_in[7];
    const float* bv   = (const float*)d_in[8];
    const float* wo   = (const float*)d_in[9];
    const float* bo   = (const float*)d_in[10];
    const float* ln2g = (const float*)d_in[11];
    const float* ln2b = (const float*)d_in[12];
    const float* c1w  = (const float*)d_in[13];
    const float* c1b  = (const float*)d_in[14];
    const float* c2w  = (const float*)d_in[15];
    const float* c2b  = (const float*)d_in[16];

    const size_t ROWS = (size_t)16 * L_;            // 32768
    char* ws = (char*)d_ws;
    size_t off = 0;
    f16* qb    = (f16*)(ws + off);   off += ROWS * HK_ * 2;  // 3.15 MB
    f16* kb    = (f16*)(ws + off);   off += ROWS * HK_ * 2;
    f16* vt    = (f16*)(ws + off);   off += (size_t)64 * 16 * 2048 * 2;   // 4.19 MB
    bf16* part_o = (bf16*)(ws + off); off += (size_t)64 * 8 * 2048 * 12 * 2; // 25.2 MB
    float* part_l = (float*)(ws + off); off += (size_t)64 * 8 * 2048 * 4;    //  4.2 MB
    bf16* wrep1 = (bf16*)(ws + off); off += 576 * 192 * 2;   // 221 KB
    bf16* wrep2 = (bf16*)(ws + off); off += 576 * 192 * 2;
    bf16* wrepq = (bf16*)(ws + off); off += 6 * 144 * 32 * 2;
    float* bias144 = (float*)(ws + off); off += 144 * 4;
    bf16* wrepo = (bf16*)(ws + off); off += 2 * 192 * 32 * 2; // total ~37 MB

    k_prep_all  <<<1021, 256, 0, stream>>>(c1w, c2w, wq, wk, wv, bq, bk, bv, wo,
                                           wrep1, wrep2, wrepq, bias144, wrepo);
    k_ln_qkv    <<<1024, 256, 0, stream>>>(x, ln1g, ln1b, wrepq, bias144, qb, kb, vt);
    k_attn_part <<<64 * 36, 256, 0, stream>>>(qb, kb, vt, part_o, part_l);
    k_mega      <<<1024, 256, 0, stream>>>(x, part_o, part_l, wrepo, bo, ln2g, ln2b,
                                           wrep1, c1b, wrep2, c2b, (float*)d_out);
}

// Round 12
// 195.175 us; speedup vs baseline: 1.0329x; 1.0204x over previous
//
#include <hip/hip_runtime.h>
#include <hip/hip_bf16.h>

#define L_ 2048
#define D_ 192
#define HK_ 48
#define EPS_ 1e-3f
#define SCALE_ 0.28867513459481287f  // 1/sqrt(12)
#define LOG2E_ 1.4426950408889634f

typedef __hip_bfloat16 bf16;
typedef _Float16 f16;
typedef __fp16 hf16x2 __attribute__((ext_vector_type(2)));   // builtin return type
typedef _Float16 f16x4 __attribute__((ext_vector_type(4)));
typedef __bf16 bf16x4 __attribute__((ext_vector_type(4)));
typedef __bf16 bf16x8 __attribute__((ext_vector_type(8)));
typedef float  f32x4  __attribute__((ext_vector_type(4)));

__device__ __forceinline__ float b2f(bf16 x) { return __bfloat162float(x); }
__device__ __forceinline__ bf16 f2b(float x) { return __float2bfloat16(x); }

// ---------------------------------------------------------------------------
// K0: single prep kernel — all weight repacks in one launch (unchanged).
// ---------------------------------------------------------------------------
__global__ __launch_bounds__(256) void k_prep_all(
    const float* __restrict__ c1w, const float* __restrict__ c2w,
    const float* __restrict__ wq, const float* __restrict__ wk, const float* __restrict__ wv,
    const float* __restrict__ bq, const float* __restrict__ bk, const float* __restrict__ bv,
    const float* __restrict__ wo,
    bf16* __restrict__ wrep1, bf16* __restrict__ wrep2,
    bf16* __restrict__ wrepq, float* __restrict__ bias144, bf16* __restrict__ wrepo)
{
    const int i = blockIdx.x * 256 + threadIdx.x;
    if (i < 110592) {
        const int k = i / 192, n = i - k * 192;
        wrep1[((size_t)(k >> 5) * 192 + n) * 32 + (k & 31)] = f2b(c1w[i]);
    } else if (i < 221184) {
        const int j = i - 110592;
        const int k = j / 192, n = j - k * 192;
        wrep2[((size_t)(k >> 5) * 192 + n) * 32 + (k & 31)] = f2b(c2w[j]);
    } else if (i < 248832) {
        const int j = i - 221184;
        const int kb = j / 4608, rem = j % 4608;
        const int n = rem / 32, kk = rem % 32;
        const int k = kb * 32 + kk;
        float v;
        if (n < 48)       v = wq[k * HK_ + n] * (SCALE_ * LOG2E_);
        else if (n < 96)  v = wk[k * HK_ + (n - 48)];
        else              v = wv[k * HK_ + (n - 96)];
        wrepq[j] = f2b(v);
    } else if (i < 248976) {
        const int j = i - 248832;
        bias144[j] = (j < 48) ? bq[j] * (SCALE_ * LOG2E_)
                   : (j < 96) ? bk[j - 48] : bv[j - 96];
    } else if (i < 261264) {
        const int j = i - 248976;
        const int kb = j / 6144, rem = j % 6144;
        const int n = rem / 32, kk = rem % 32;
        const int k = kb * 32 + kk;
        wrepo[j] = f2b(k < 48 ? wo[k * D_ + n] : 0.f);
    }
}

// ---------------------------------------------------------------------------
// K1: fused LN1 + QKV projection via MFMA (unchanged; q/k head-contiguous
// [b*4+h][2048][12]).
// ---------------------------------------------------------------------------
__global__ __launch_bounds__(256, 4) void k_ln_qkv(
    const float* __restrict__ x, const float* __restrict__ g1, const float* __restrict__ b1,
    const bf16* __restrict__ wrep, const float* __restrict__ bias144,
    f16* __restrict__ qo, f16* __restrict__ ko, f16* __restrict__ vt)
{
    __shared__ bf16 xn[32 * 200];
    const int tid = threadIdx.x;
    const int wave = tid >> 6, lane = tid & 63;
    const int rowbase = blockIdx.x * 32;
    const int b = rowbase >> 11;
    const int lrow0 = rowbase & 2047;

    const float gg0 = g1[lane], gg1 = g1[lane + 64], gg2 = g1[lane + 128];
    const float bb0 = b1[lane], bb1 = b1[lane + 64], bb2 = b1[lane + 128];
    for (int i = 0; i < 8; ++i) {
        const int r = wave * 8 + i;
        const float* xp = x + (size_t)(rowbase + r) * D_;
        const float x0 = xp[lane];
        const float x1 = xp[lane + 64];
        const float x2 = xp[lane + 128];
        float s = x0 + x1 + x2;
        float q = x0 * x0 + x1 * x1 + x2 * x2;
        #pragma unroll
        for (int m = 1; m < 64; m <<= 1) {
            s += __shfl_xor(s, m, 64);
            q += __shfl_xor(q, m, 64);
        }
        const float mean = s * (1.0f / 192.0f);
        const float var  = q * (1.0f / 192.0f) - mean * mean;
        const float rs   = rsqrtf(var + EPS_);
        xn[r * 200 + lane]       = f2b((x0 - mean) * rs * gg0 + bb0);
        xn[r * 200 + lane + 64]  = f2b((x1 - mean) * rs * gg1 + bb1);
        xn[r * 200 + lane + 128] = f2b((x2 - mean) * rs * gg2 + bb2);
    }

    if (tid < 128) {
        const int h  = tid >> 5;
        const int vc = 12 + ((tid >> 3) & 3);
        const int p0 = lrow0 + (tid & 7) * 4;
        f16x4 vv;
        vv[0] = vv[1] = vv[2] = vv[3] = (vc == 12) ? (f16)1.0f : (f16)0.0f;
        *(f16x4*)(vt + ((size_t)(b * 4 + h) * 16 + vc) * 2048 + p0) = vv;
    }
    __syncthreads();

    const int l15 = lane & 15, q4 = lane >> 4;
    const int rt = wave >> 1, g = wave & 1;
    const int ntlim = 5 - g;                 // g=0: nt 0..4, g=1: nt 0..3 (+5)
    f32x4 acc[5];
    #pragma unroll
    for (int nt = 0; nt < 5; ++nt) acc[nt] = (f32x4){0.f, 0.f, 0.f, 0.f};

    const bf16* xrow = xn + (rt * 16 + l15) * 200 + q4 * 8;
    #pragma unroll
    for (int kb = 0; kb < 6; ++kb) {
        const bf16x8 a = *(const bf16x8*)(xrow + kb * 32);
        const bf16* wp = wrep + ((size_t)kb * 144 + l15) * 32 + q4 * 8
                       + (size_t)(g * 5) * 16 * 32;
        #pragma unroll
        for (int nt = 0; nt < 5; ++nt) {
            if (nt < ntlim) {
                const bf16x8 bfr = *(const bf16x8*)(wp + (size_t)nt * 16 * 32);
                acc[nt] = __builtin_amdgcn_mfma_f32_16x16x32_bf16(a, bfr, acc[nt], 0, 0, 0);
            }
        }
    }

    const int lr0 = lrow0 + rt * 16 + q4 * 4;
    #pragma unroll
    for (int nt = 0; nt < 5; ++nt) {
        if (nt < ntlim) {
            const int ntg = g * 5 + nt;
            const int col = ntg * 16 + l15;
            const float bd = bias144[col];
            if (ntg < 3) {
                const int h2 = col / 12, c12 = col - h2 * 12;
                #pragma unroll
                for (int reg = 0; reg < 4; ++reg)
                    qo[((size_t)(b * 4 + h2) * 2048 + lr0 + reg) * 12 + c12] =
                        (f16)(acc[nt][reg] + bd);
            } else if (ntg < 6) {
                const int ck = col - 48;
                const int h2 = ck / 12, c12 = ck - h2 * 12;
                #pragma unroll
                for (int reg = 0; reg < 4; ++reg)
                    ko[((size_t)(b * 4 + h2) * 2048 + lr0 + reg) * 12 + c12] =
                        (f16)(acc[nt][reg] + bd);
            } else {
                const int vcol = col - 96;
                const int h = vcol / 12, c12 = vcol % 12;
                f16x4 vv;
                #pragma unroll
                for (int reg = 0; reg < 4; ++reg) vv[reg] = (f16)(acc[nt][reg] + bd);
                *(f16x4*)(vt + ((size_t)(b * 4 + h) * 16 + c12) * 2048 +
                          lrow0 + rt * 16 + q4 * 4) = vv;
            }
        }
    }
}

// ---------------------------------------------------------------------------
// K2: split-k partials attention (exact r7-proven form).
// ---------------------------------------------------------------------------
__global__ __launch_bounds__(256, 8) void k_attn_part(
    const f16* __restrict__ qh, const f16* __restrict__ kh, const f16* __restrict__ vt,
    bf16* __restrict__ part_o, float* __restrict__ part_l)
{
    const int tid = threadIdx.x;
    const int wv = tid >> 6, lane = tid & 63;
    const int quad = lane >> 4, l15 = lane & 15;
    const int bh = blockIdx.x / 36;
    int r = blockIdx.x % 36;
    int qt = 0;
    while (r >= qt + 1) { r -= qt + 1; ++qt; }
    const int ks = r;
    const size_t base  = (size_t)bh * 2048 * 12;          // head-contiguous
    const size_t vbase = ((size_t)bh * 16 + l15) * 2048;
    const int kbase = ks * 256;
    const int qbase = qt * 256 + wv * 64;
    const bool diag = (ks == qt);
    const int ktmax = diag ? 4 * (wv + 1) : 16;

    f16x4 Qf[4];
    #pragma unroll
    for (int s = 0; s < 4; ++s) {
        f16x4 v;
        if (quad < 3)
            v = *(const f16x4*)(qh + base + (size_t)(qbase + s * 16 + l15) * 12 + quad * 4);
        else { v[0] = (f16)LOG2E_; v[1] = 0; v[2] = 0; v[3] = 0; }   // hd12 = log2e
        Qf[s] = v;
    }

    f32x4 O[4];
    #pragma unroll
    for (int s = 0; s < 4; ++s) O[s] = (f32x4){0.f, 0.f, 0.f, 0.f};

    for (int g = 0; g < ktmax; g += 2) {
        f16x4 Kg[2], Vg[2];
        #pragma unroll
        for (int u = 0; u < 2; ++u) {
            const int kt = g + u;
            f16x4 kf;
            if (quad < 3)
                kf = *(const f16x4*)(kh + base + (size_t)(kbase + kt * 16 + l15) * 12 + quad * 4);
            else { kf[0] = (f16)-6.0f; kf[1] = 0; kf[2] = 0; kf[3] = 0; } // hd12 = -6
            Kg[u] = kf;
            Vg[u] = *(const f16x4*)(vt + vbase + kbase + kt * 16 + quad * 4);
        }
        #pragma unroll
        for (int u = 0; u < 2; ++u) {
            const int k0 = kbase + (g + u) * 16 + quad * 4;
            #pragma unroll
            for (int s = 0; s < 4; ++s) {
                f32x4 sc = (f32x4){0.f, 0.f, 0.f, 0.f};
                sc = __builtin_amdgcn_mfma_f32_16x16x16f16(Kg[u], Qf[s], sc, 0, 0, 0);
                float p0 = __builtin_amdgcn_exp2f(sc[0]);
                float p1 = __builtin_amdgcn_exp2f(sc[1]);
                float p2 = __builtin_amdgcn_exp2f(sc[2]);
                float p3 = __builtin_amdgcn_exp2f(sc[3]);
                if (diag) {
                    const int qg = qbase + s * 16 + l15;
                    p0 = (k0 + 0 <= qg) ? p0 : 0.f;
                    p1 = (k0 + 1 <= qg) ? p1 : 0.f;
                    p2 = (k0 + 2 <= qg) ? p2 : 0.f;
                    p3 = (k0 + 3 <= qg) ? p3 : 0.f;
                }
                const hf16x2 lo = __builtin_amdgcn_cvt_pkrtz(p0, p1);
                const hf16x2 hi = __builtin_amdgcn_cvt_pkrtz(p2, p3);
                f16x4 p;
                p[0] = (f16)lo[0]; p[1] = (f16)lo[1];
                p[2] = (f16)hi[0]; p[3] = (f16)hi[1];
                O[s] = __builtin_amdgcn_mfma_f32_16x16x16f16(p, Vg[u], O[s], 0, 0, 0);
            }
        }
    }

    const size_t pobase = (size_t)(bh * 8 + ks) * 2048;
    #pragma unroll
    for (int s = 0; s < 4; ++s) {
        const int q16 = qbase + s * 16;
        #pragma unroll
        for (int j = 0; j < 4; ++j) {
            const int qq = q16 + quad * 4 + j;
            if (l15 < 12)       part_o[(pobase + qq) * 12 + l15] = f2b(O[s][j]);
            else if (l15 == 12) part_l[pobase + qq] = O[s][j];
        }
    }
}

// ---------------------------------------------------------------------------
// K3: MEGA — exact r7 structure ((256,3), x2 tile in LDS, dynamic combine
// loop; measured 54.7 µs clean). Round-12 change: kill the 1.98M LDS bank
// conflicts. Scalar bf16 tile writes at stride 400 alias lane groups q and
// q+2 (row distance 8 -> 8*100 dw = 0 mod 32 -> 4-way); x2's old stride 384
// (96 dw = 0 mod 32) aliased ALL rows. Fix: all three tiles (conv-in, h,
// x2@stride-400) get byte-in-row XOR ((row>>3)&1)<<5 on BOTH write and read
// sides — stays inside the 384-B row, preserves b128 16-B alignment
// (chunks contiguous: XOR bit above bit 3), separates q/q+2 into disjoint
// 8-dword blocks (writes -> 2-way = free), reads stay <=2-way.
// ---------------------------------------------------------------------------
#define CIROWB 400
#define R2OFF  14400              // 36*400 : union { ct[48][72] | h-tile 34 rows }
#define X2OFF  28000              // R2OFF + 34*400
#define PSOFF  40800              // X2OFF + 32*400
#define SWZ(row) ((((row) >> 3) & 1) << 5)
__global__ __launch_bounds__(256, 3) void k_mega(
    const float* __restrict__ x, const bf16* __restrict__ part_o,
    const float* __restrict__ part_l, const bf16* __restrict__ wrepo,
    const float* __restrict__ bo, const float* __restrict__ g2,
    const float* __restrict__ lb2, const bf16* __restrict__ w1,
    const float* __restrict__ b1c, const bf16* __restrict__ w2,
    const float* __restrict__ b2c, float* __restrict__ outf)
{
    __shared__ __align__(16) char lds[42336];
    bf16* ct = (bf16*)(lds + R2OFF);          // [48][72] proj A-tile

    const int tid = threadIdx.x;
    const int wave = tid >> 6, lane = tid & 63;
    const int m16 = lane & 15, q = lane >> 4;
    const int rowbase = blockIdx.x * 32;
    const int b = rowbase >> 11, lrow = rowbase & 2047;
    const int colw = wave * 48;

    // ---- phase A0: combine partials for 36 halo rows (tile rows 0..35) ----
    if (tid < 144) {
        const int rr = tid >> 2, h = tid & 3;
        int qrow = lrow + rr - 2;
        qrow = qrow < 0 ? 0 : (qrow > 2047 ? 2047 : qrow);
        const int nsq = (qrow >> 8) + 1;       // segments valid for this row
        const size_t sb = (size_t)(b * 4 + h) * 8 * 2048 + qrow;
        float o[12];
        #pragma unroll
        for (int i = 0; i < 12; ++i) o[i] = 0.f;
        float l = 0.f;
        for (int s = 0; s < nsq; ++s) {
            l += part_l[sb + (size_t)s * 2048];
            const bf16x8 v8 = *(const bf16x8*)(part_o + (sb + (size_t)s * 2048) * 12);
            const bf16x4 v4 = *(const bf16x4*)(part_o + (sb + (size_t)s * 2048) * 12 + 8);
            #pragma unroll
            for (int i = 0; i < 8; ++i) o[i] += (float)v8[i];
            #pragma unroll
            for (int i = 0; i < 4; ++i) o[8 + i] += (float)v4[i];
        }
        const float inv = 1.0f / l;
        bf16* ctp = ct + rr * 72 + h * 12;
        #pragma unroll
        for (int i = 0; i < 12; ++i) ctp[i] = f2b(o[i] * inv);
        bf16x4 z;
        #pragma unroll
        for (int i = 0; i < 4; ++i) z[i] = (__bf16)0.0f;
        *(bf16x4*)(ct + rr * 72 + 48 + h * 4) = z;   // zero K-pad cols 48..63
    } else {
        const int idx = tid - 144;             // zero ct rows 36..47
        if (idx < 108) {
            bf16x8 z;
            #pragma unroll
            for (int i = 0; i < 8; ++i) z[i] = (__bf16)0.0f;
            *(bf16x8*)(ct + 36 * 72 + idx * 8) = z;
        }
    }
    float bd1[3], bd2[3], gg2[3], bbl2[3], bod[3];
    #pragma unroll
    for (int j = 0; j < 3; ++j) {
        const int col = colw + j * 16 + m16;
        bd1[j] = b1c[col]; bd2[j] = b2c[col];
        gg2[j] = g2[col];  bbl2[j] = lb2[col]; bod[j] = bo[col];
    }
    __syncthreads();

    // ---- phase A1: proj MFMA, 3 M-tiles (48 rows, 36 live) x 3 N-tiles ----
    f32x4 pv[3][3];
    #pragma unroll
    for (int mt = 0; mt < 3; ++mt)
        #pragma unroll
        for (int j = 0; j < 3; ++j) pv[mt][j] = (f32x4){0.f, 0.f, 0.f, 0.f};
    #pragma unroll
    for (int kb = 0; kb < 2; ++kb) {
        bf16x8 a[3];
        #pragma unroll
        for (int mt = 0; mt < 3; ++mt)
            a[mt] = *(const bf16x8*)(ct + (mt * 16 + m16) * 72 + kb * 32 + q * 8);
        #pragma unroll
        for (int j = 0; j < 3; ++j) {
            const bf16x8 bb = *(const bf16x8*)(wrepo +
                ((size_t)kb * 192 + (size_t)(wave * 3 + j) * 16 + m16) * 32 + q * 8);
            #pragma unroll
            for (int mt = 0; mt < 3; ++mt)
                pv[mt][j] = __builtin_amdgcn_mfma_f32_16x16x32_bf16(a[mt], bb, pv[mt][j], 0, 0, 0);
        }
    }

    // ---- bias + residual x -> v; per-row sum/ssq (48-col partial per wave) ----
    #pragma unroll
    for (int mt = 0; mt < 3; ++mt) {
        const bool live = (mt < 2) || (q == 0);
        #pragma unroll
        for (int j = 0; j < 3; ++j) {
            const int col = colw + j * 16 + m16;
            #pragma unroll
            for (int reg = 0; reg < 4; ++reg) {
                int grow = lrow + mt * 16 + q * 4 + reg - 2;
                grow = grow < 0 ? 0 : (grow > 2047 ? 2047 : grow);
                float v = 0.f;
                if (live)
                    v = pv[mt][j][reg] + bod[j] + x[((size_t)b * 2048 + grow) * D_ + col];
                pv[mt][j][reg] = v;
            }
        }
    }
    {
        float* ps = (float*)(lds + PSOFF);     // [4][48][2]
        #pragma unroll
        for (int mt = 0; mt < 3; ++mt) {
            float sum[4], ssq[4];
            #pragma unroll
            for (int reg = 0; reg < 4; ++reg) {
                sum[reg] = pv[mt][0][reg] + pv[mt][1][reg] + pv[mt][2][reg];
                ssq[reg] = pv[mt][0][reg] * pv[mt][0][reg]
                         + pv[mt][1][reg] * pv[mt][1][reg]
                         + pv[mt][2][reg] * pv[mt][2][reg];
            }
            #pragma unroll
            for (int m = 1; m <= 8; m <<= 1) {
                #pragma unroll
                for (int reg = 0; reg < 4; ++reg) {
                    sum[reg] += __shfl_xor(sum[reg], m, 64);
                    ssq[reg] += __shfl_xor(ssq[reg], m, 64);
                }
            }
            if (m16 == 0) {
                #pragma unroll
                for (int reg = 0; reg < 4; ++reg) {
                    const int tr = mt * 16 + q * 4 + reg;
                    ps[(wave * 48 + tr) * 2 + 0] = sum[reg];
                    ps[(wave * 48 + tr) * 2 + 1] = ssq[reg];
                }
            }
        }
    }
    __syncthreads();

    // ---- LN2 stats; write xn2 -> conv-input tile, v -> x2 tile (swizzled) ----
    {
        const float* ps = (const float*)(lds + PSOFF);
        #pragma unroll
        for (int mt = 0; mt < 3; ++mt) {
            const bool live = (mt < 2) || (q == 0);
            float mean[4], rs[4];
            #pragma unroll
            for (int reg = 0; reg < 4; ++reg) {
                const int tr = mt * 16 + q * 4 + reg;
                float st = 0.f, sq = 0.f;
                #pragma unroll
                for (int w = 0; w < 4; ++w) {
                    st += ps[(w * 48 + tr) * 2 + 0];
                    sq += ps[(w * 48 + tr) * 2 + 1];
                }
                mean[reg] = st * (1.0f / 192.0f);
                const float var = sq * (1.0f / 192.0f) - mean[reg] * mean[reg];
                rs[reg] = rsqrtf(var + EPS_);
            }
            if (live) {
                #pragma unroll
                for (int j = 0; j < 3; ++j) {
                    const int col = colw + j * 16 + m16;
                    #pragma unroll
                    for (int reg = 0; reg < 4; ++reg) {
                        const int tr = mt * 16 + q * 4 + reg;
                        const float v = pv[mt][j][reg];
                        const float xn = (v - mean[reg]) * rs[reg] * gg2[j] + bbl2[j];
                        *(bf16*)(lds + tr * CIROWB + ((col * 2) ^ SWZ(tr))) = f2b(xn);
                        if (tr >= 2 && tr < 34)
                            *(bf16*)(lds + X2OFF + (tr - 2) * CIROWB +
                                     ((col * 2) ^ SWZ(tr - 2))) = f2b(v);
                    }
                }
            }
        }
    }
    __syncthreads();

    // ---- phase B: conv1 (3 M-tiles, 34 valid h rows) ----
    f32x4 acc1[3][3];
    #pragma unroll
    for (int mt = 0; mt < 3; ++mt)
        #pragma unroll
        for (int j = 0; j < 3; ++j) acc1[mt][j] = (f32x4){0.f, 0.f, 0.f, 0.f};

    #define LOADB(w, kb, j) \
        (*(const bf16x8*)((w) + ((size_t)(kb) * 192 + m16) * 32 + q * 8 \
                          + (size_t)(wave * 3 + (j)) * 16 * 32))
    {
        bf16x8 bB[2][3];
        #pragma unroll
        for (int j = 0; j < 3; ++j) bB[0][j] = LOADB(w1, 0, j);
        #pragma unroll
        for (int kb = 0; kb < 18; ++kb) {
            if (kb + 1 < 18) {
                #pragma unroll
                for (int j = 0; j < 3; ++j) bB[(kb + 1) & 1][j] = LOADB(w1, kb + 1, j);
            }
            const int t = kb / 6, c6 = kb % 6;
            const int boff = (q * 16 + c6 * 64) ^ SWZ(m16 + t);
            const int rbase = (m16 + t) * CIROWB;
            bf16x8 a[3];
            #pragma unroll
            for (int mt = 0; mt < 3; ++mt)
                a[mt] = *(const bf16x8*)(lds + rbase + mt * 16 * CIROWB + boff);
            #pragma unroll
            for (int j = 0; j < 3; ++j)
                #pragma unroll
                for (int mt = 0; mt < 3; ++mt)
                    acc1[mt][j] = __builtin_amdgcn_mfma_f32_16x16x32_bf16(
                        a[mt], bB[kb & 1][j], acc1[mt][j], 0, 0, 0);
        }
    }

    // ---- h-tile (relu, edge-zero) -> LDS region2 rows 0..33 (swizzled) ----
    #pragma unroll
    for (int mt = 0; mt < 3; ++mt)
        #pragma unroll
        for (int j = 0; j < 3; ++j)
            #pragma unroll
            for (int reg = 0; reg < 4; ++reg) {
                const int hr = mt * 16 + q * 4 + reg;
                if (hr < 34) {
                    const int hm = lrow + hr - 1;
                    float v = fmaxf(acc1[mt][j][reg] + bd1[j], 0.f);
                    if (hm == 0 || hm == L_ - 1) v = 0.f;
                    *(bf16*)(lds + R2OFF + hr * CIROWB +
                             (((colw + j * 16 + m16) * 2) ^ SWZ(hr))) = f2b(v);
                }
            }
    __syncthreads();

    // ---- conv2: 2 M-tiles x 3 N-tiles, A from h-tile (swizzled reads) ----
    f32x4 acc2[2][3];
    #pragma unroll
    for (int mt = 0; mt < 2; ++mt)
        #pragma unroll
        for (int j = 0; j < 3; ++j) acc2[mt][j] = (f32x4){0.f, 0.f, 0.f, 0.f};
    {
        bf16x8 bB[2][3];
        #pragma unroll
        for (int j = 0; j < 3; ++j) bB[0][j] = LOADB(w2, 0, j);
        #pragma unroll
        for (int kb = 0; kb < 18; ++kb) {
            if (kb + 1 < 18) {
                #pragma unroll
                for (int j = 0; j < 3; ++j) bB[(kb + 1) & 1][j] = LOADB(w2, kb + 1, j);
            }
            const int t = kb / 6, c6 = kb % 6;
            const int boff = (q * 16 + c6 * 64) ^ SWZ(m16 + t);
            const int rbase = (m16 + t) * CIROWB;
            bf16x8 a[2];
            #pragma unroll
            for (int mt = 0; mt < 2; ++mt)
                a[mt] = *(const bf16x8*)(lds + R2OFF + rbase + mt * 16 * CIROWB + boff);
            #pragma unroll
            for (int j = 0; j < 3; ++j)
                #pragma unroll
                for (int mt = 0; mt < 2; ++mt)
                    acc2[mt][j] = __builtin_amdgcn_mfma_f32_16x16x32_bf16(
                        a[mt], bB[kb & 1][j], acc2[mt][j], 0, 0, 0);
        }
    }
    #undef LOADB

    // ---- epilogue: residual (x+mha from x2 tile, swizzled) + conv2 + store ----
    #pragma unroll
    for (int j = 0; j < 3; ++j)
        #pragma unroll
        for (int mt = 0; mt < 2; ++mt)
            #pragma unroll
            for (int reg = 0; reg < 4; ++reg) {
                const int orr = mt * 16 + q * 4 + reg;
                const int r = rowbase + orr;
                const int m = r & (L_ - 1);
                const int col = colw + j * 16 + m16;
                float v = b2f(*(const bf16*)(lds + X2OFF + orr * CIROWB +
                                             ((col * 2) ^ SWZ(orr))));
                if (m != 0 && m != L_ - 1) v += acc2[mt][j][reg] + bd2[j];
                outf[(size_t)r * D_ + col] = v;
            }
}

// ---------------------------------------------------------------------------
extern "C" void kernel_launch(void* const* d_in, const int* in_sizes, int n_in,
                              void* d_out, int out_size, void* d_ws, size_t ws_size,
                              hipStream_t stream)
{
    const float* x    = (const float*)d_in[0];
    const float* ln1g = (const float*)d_in[1];
    const float* ln1b = (const float*)d_in[2];
    const float* wq   = (const float*)d_in[3];
    const float* bq   = (const float*)d_in[4];
    const float* wk   = (const float*)d_in[5];
    const float* bk   = (const float*)d_in[6];
    const float* wv   = (const float*)d_in[7];
    const float* bv   = (const float*)d_in[8];
    const float* wo   = (const float*)d_in[9];
    const float* bo   = (const float*)d_in[10];
    const float* ln2g = (const float*)d_in[11];
    const float* ln2b = (const float*)d_in[12];
    const float* c1w  = (const float*)d_in[13];
    const float* c1b  = (const float*)d_in[14];
    const float* c2w  = (const float*)d_in[15];
    const float* c2b  = (const float*)d_in[16];

    const size_t ROWS = (size_t)16 * L_;            // 32768
    char* ws = (char*)d_ws;
    size_t off = 0;
    f16* qb    = (f16*)(ws + off);   off += ROWS * HK_ * 2;  // 3.15 MB
    f16* kb    = (f16*)(ws + off);   off += ROWS * HK_ * 2;
    f16* vt    = (f16*)(ws + off);   off += (size_t)64 * 16 * 2048 * 2;   // 4.19 MB
    bf16* part_o = (bf16*)(ws + off); off += (size_t)64 * 8 * 2048 * 12 * 2; // 25.2 MB
    float* part_l = (float*)(ws + off); off += (size_t)64 * 8 * 2048 * 4;    //  4.2 MB
    bf16* wrep1 = (bf16*)(ws + off); off += 576 * 192 * 2;   // 221 KB
    bf16* wrep2 = (bf16*)(ws + off); off += 576 * 192 * 2;
    bf16* wrepq = (bf16*)(ws + off); off += 6 * 144 * 32 * 2;
    float* bias144 = (float*)(ws + off); off += 144 * 4;
    bf16* wrepo = (bf16*)(ws + off); off += 2 * 192 * 32 * 2; // total ~37 MB

    k_prep_all  <<<1021, 256, 0, stream>>>(c1w, c2w, wq, wk, wv, bq, bk, bv, wo,
                                           wrep1, wrep2, wrepq, bias144, wrepo);
    k_ln_qkv    <<<1024, 256, 0, stream>>>(x, ln1g, ln1b, wrepq, bias144, qb, kb, vt);
    k_attn_part <<<64 * 36, 256, 0, stream>>>(qb, kb, vt, part_o, part_l);
    k_mega      <<<1024, 256, 0, stream>>>(x, part_o, part_l, wrepo, bo, ln2g, ln2b,
                                           wrep1, c1b, wrep2, c2b, (float*)d_out);
}

// Round 13
// 193.069 us; speedup vs baseline: 1.0442x; 1.0109x over previous
//
#include <hip/hip_runtime.h>
#include <hip/hip_bf16.h>

#define L_ 2048
#define D_ 192
#define HK_ 48
#define EPS_ 1e-3f
#define SCALE_ 0.28867513459481287f  // 1/sqrt(12)
#define LOG2E_ 1.4426950408889634f

typedef __hip_bfloat16 bf16;
typedef _Float16 f16;
typedef __fp16 hf16x2 __attribute__((ext_vector_type(2)));   // builtin return type
typedef _Float16 f16x4 __attribute__((ext_vector_type(4)));
typedef __bf16 bf16x4 __attribute__((ext_vector_type(4)));
typedef __bf16 bf16x8 __attribute__((ext_vector_type(8)));
typedef float  f32x4  __attribute__((ext_vector_type(4)));

__device__ __forceinline__ float b2f(bf16 x) { return __bfloat162float(x); }
__device__ __forceinline__ bf16 f2b(float x) { return __float2bfloat16(x); }

// ---------------------------------------------------------------------------
// K0: single prep kernel — all weight repacks in one launch (unchanged).
// ---------------------------------------------------------------------------
__global__ __launch_bounds__(256) void k_prep_all(
    const float* __restrict__ c1w, const float* __restrict__ c2w,
    const float* __restrict__ wq, const float* __restrict__ wk, const float* __restrict__ wv,
    const float* __restrict__ bq, const float* __restrict__ bk, const float* __restrict__ bv,
    const float* __restrict__ wo,
    bf16* __restrict__ wrep1, bf16* __restrict__ wrep2,
    bf16* __restrict__ wrepq, float* __restrict__ bias144, bf16* __restrict__ wrepo)
{
    const int i = blockIdx.x * 256 + threadIdx.x;
    if (i < 110592) {
        const int k = i / 192, n = i - k * 192;
        wrep1[((size_t)(k >> 5) * 192 + n) * 32 + (k & 31)] = f2b(c1w[i]);
    } else if (i < 221184) {
        const int j = i - 110592;
        const int k = j / 192, n = j - k * 192;
        wrep2[((size_t)(k >> 5) * 192 + n) * 32 + (k & 31)] = f2b(c2w[j]);
    } else if (i < 248832) {
        const int j = i - 221184;
        const int kb = j / 4608, rem = j % 4608;
        const int n = rem / 32, kk = rem % 32;
        const int k = kb * 32 + kk;
        float v;
        if (n < 48)       v = wq[k * HK_ + n] * (SCALE_ * LOG2E_);
        else if (n < 96)  v = wk[k * HK_ + (n - 48)];
        else              v = wv[k * HK_ + (n - 96)];
        wrepq[j] = f2b(v);
    } else if (i < 248976) {
        const int j = i - 248832;
        bias144[j] = (j < 48) ? bq[j] * (SCALE_ * LOG2E_)
                   : (j < 96) ? bk[j - 48] : bv[j - 96];
    } else if (i < 261264) {
        const int j = i - 248976;
        const int kb = j / 6144, rem = j % 6144;
        const int n = rem / 32, kk = rem % 32;
        const int k = kb * 32 + kk;
        wrepo[j] = f2b(k < 48 ? wo[k * D_ + n] : 0.f);
    }
}

// ---------------------------------------------------------------------------
// K1: fused LN1 + QKV projection via MFMA (r7-exact; q/k head-contiguous
// [b*4+h][2048][12]).
// ---------------------------------------------------------------------------
__global__ __launch_bounds__(256, 4) void k_ln_qkv(
    const float* __restrict__ x, const float* __restrict__ g1, const float* __restrict__ b1,
    const bf16* __restrict__ wrep, const float* __restrict__ bias144,
    f16* __restrict__ qo, f16* __restrict__ ko, f16* __restrict__ vt)
{
    __shared__ bf16 xn[32 * 200];
    const int tid = threadIdx.x;
    const int wave = tid >> 6, lane = tid & 63;
    const int rowbase = blockIdx.x * 32;
    const int b = rowbase >> 11;
    const int lrow0 = rowbase & 2047;

    const float gg0 = g1[lane], gg1 = g1[lane + 64], gg2 = g1[lane + 128];
    const float bb0 = b1[lane], bb1 = b1[lane + 64], bb2 = b1[lane + 128];
    for (int i = 0; i < 8; ++i) {
        const int r = wave * 8 + i;
        const float* xp = x + (size_t)(rowbase + r) * D_;
        const float x0 = xp[lane];
        const float x1 = xp[lane + 64];
        const float x2 = xp[lane + 128];
        float s = x0 + x1 + x2;
        float q = x0 * x0 + x1 * x1 + x2 * x2;
        #pragma unroll
        for (int m = 1; m < 64; m <<= 1) {
            s += __shfl_xor(s, m, 64);
            q += __shfl_xor(q, m, 64);
        }
        const float mean = s * (1.0f / 192.0f);
        const float var  = q * (1.0f / 192.0f) - mean * mean;
        const float rs   = rsqrtf(var + EPS_);
        xn[r * 200 + lane]       = f2b((x0 - mean) * rs * gg0 + bb0);
        xn[r * 200 + lane + 64]  = f2b((x1 - mean) * rs * gg1 + bb1);
        xn[r * 200 + lane + 128] = f2b((x2 - mean) * rs * gg2 + bb2);
    }

    if (tid < 128) {
        const int h  = tid >> 5;
        const int vc = 12 + ((tid >> 3) & 3);
        const int p0 = lrow0 + (tid & 7) * 4;
        f16x4 vv;
        vv[0] = vv[1] = vv[2] = vv[3] = (vc == 12) ? (f16)1.0f : (f16)0.0f;
        *(f16x4*)(vt + ((size_t)(b * 4 + h) * 16 + vc) * 2048 + p0) = vv;
    }
    __syncthreads();

    const int l15 = lane & 15, q4 = lane >> 4;
    const int rt = wave >> 1, g = wave & 1;
    const int ntlim = 5 - g;                 // g=0: nt 0..4, g=1: nt 0..3 (+5)
    f32x4 acc[5];
    #pragma unroll
    for (int nt = 0; nt < 5; ++nt) acc[nt] = (f32x4){0.f, 0.f, 0.f, 0.f};

    const bf16* xrow = xn + (rt * 16 + l15) * 200 + q4 * 8;
    #pragma unroll
    for (int kb = 0; kb < 6; ++kb) {
        const bf16x8 a = *(const bf16x8*)(xrow + kb * 32);
        const bf16* wp = wrep + ((size_t)kb * 144 + l15) * 32 + q4 * 8
                       + (size_t)(g * 5) * 16 * 32;
        #pragma unroll
        for (int nt = 0; nt < 5; ++nt) {
            if (nt < ntlim) {
                const bf16x8 bfr = *(const bf16x8*)(wp + (size_t)nt * 16 * 32);
                acc[nt] = __builtin_amdgcn_mfma_f32_16x16x32_bf16(a, bfr, acc[nt], 0, 0, 0);
            }
        }
    }

    const int lr0 = lrow0 + rt * 16 + q4 * 4;
    #pragma unroll
    for (int nt = 0; nt < 5; ++nt) {
        if (nt < ntlim) {
            const int ntg = g * 5 + nt;
            const int col = ntg * 16 + l15;
            const float bd = bias144[col];
            if (ntg < 3) {
                const int h2 = col / 12, c12 = col - h2 * 12;
                #pragma unroll
                for (int reg = 0; reg < 4; ++reg)
                    qo[((size_t)(b * 4 + h2) * 2048 + lr0 + reg) * 12 + c12] =
                        (f16)(acc[nt][reg] + bd);
            } else if (ntg < 6) {
                const int ck = col - 48;
                const int h2 = ck / 12, c12 = ck - h2 * 12;
                #pragma unroll
                for (int reg = 0; reg < 4; ++reg)
                    ko[((size_t)(b * 4 + h2) * 2048 + lr0 + reg) * 12 + c12] =
                        (f16)(acc[nt][reg] + bd);
            } else {
                const int vcol = col - 96;
                const int h = vcol / 12, c12 = vcol % 12;
                f16x4 vv;
                #pragma unroll
                for (int reg = 0; reg < 4; ++reg) vv[reg] = (f16)(acc[nt][reg] + bd);
                *(f16x4*)(vt + ((size_t)(b * 4 + h) * 16 + c12) * 2048 +
                          lrow0 + rt * 16 + q4 * 4) = vv;
            }
        }
    }
}

// ---------------------------------------------------------------------------
// K2: split-k partials attention (r7-exact).
// ---------------------------------------------------------------------------
__global__ __launch_bounds__(256, 8) void k_attn_part(
    const f16* __restrict__ qh, const f16* __restrict__ kh, const f16* __restrict__ vt,
    bf16* __restrict__ part_o, float* __restrict__ part_l)
{
    const int tid = threadIdx.x;
    const int wv = tid >> 6, lane = tid & 63;
    const int quad = lane >> 4, l15 = lane & 15;
    const int bh = blockIdx.x / 36;
    int r = blockIdx.x % 36;
    int qt = 0;
    while (r >= qt + 1) { r -= qt + 1; ++qt; }
    const int ks = r;
    const size_t base  = (size_t)bh * 2048 * 12;          // head-contiguous
    const size_t vbase = ((size_t)bh * 16 + l15) * 2048;
    const int kbase = ks * 256;
    const int qbase = qt * 256 + wv * 64;
    const bool diag = (ks == qt);
    const int ktmax = diag ? 4 * (wv + 1) : 16;

    f16x4 Qf[4];
    #pragma unroll
    for (int s = 0; s < 4; ++s) {
        f16x4 v;
        if (quad < 3)
            v = *(const f16x4*)(qh + base + (size_t)(qbase + s * 16 + l15) * 12 + quad * 4);
        else { v[0] = (f16)LOG2E_; v[1] = 0; v[2] = 0; v[3] = 0; }   // hd12 = log2e
        Qf[s] = v;
    }

    f32x4 O[4];
    #pragma unroll
    for (int s = 0; s < 4; ++s) O[s] = (f32x4){0.f, 0.f, 0.f, 0.f};

    for (int g = 0; g < ktmax; g += 2) {
        f16x4 Kg[2], Vg[2];
        #pragma unroll
        for (int u = 0; u < 2; ++u) {
            const int kt = g + u;
            f16x4 kf;
            if (quad < 3)
                kf = *(const f16x4*)(kh + base + (size_t)(kbase + kt * 16 + l15) * 12 + quad * 4);
            else { kf[0] = (f16)-6.0f; kf[1] = 0; kf[2] = 0; kf[3] = 0; } // hd12 = -6
            Kg[u] = kf;
            Vg[u] = *(const f16x4*)(vt + vbase + kbase + kt * 16 + quad * 4);
        }
        #pragma unroll
        for (int u = 0; u < 2; ++u) {
            const int k0 = kbase + (g + u) * 16 + quad * 4;
            #pragma unroll
            for (int s = 0; s < 4; ++s) {
                f32x4 sc = (f32x4){0.f, 0.f, 0.f, 0.f};
                sc = __builtin_amdgcn_mfma_f32_16x16x16f16(Kg[u], Qf[s], sc, 0, 0, 0);
                float p0 = __builtin_amdgcn_exp2f(sc[0]);
                float p1 = __builtin_amdgcn_exp2f(sc[1]);
                float p2 = __builtin_amdgcn_exp2f(sc[2]);
                float p3 = __builtin_amdgcn_exp2f(sc[3]);
                if (diag) {
                    const int qg = qbase + s * 16 + l15;
                    p0 = (k0 + 0 <= qg) ? p0 : 0.f;
                    p1 = (k0 + 1 <= qg) ? p1 : 0.f;
                    p2 = (k0 + 2 <= qg) ? p2 : 0.f;
                    p3 = (k0 + 3 <= qg) ? p3 : 0.f;
                }
                const hf16x2 lo = __builtin_amdgcn_cvt_pkrtz(p0, p1);
                const hf16x2 hi = __builtin_amdgcn_cvt_pkrtz(p2, p3);
                f16x4 p;
                p[0] = (f16)lo[0]; p[1] = (f16)lo[1];
                p[2] = (f16)hi[0]; p[3] = (f16)hi[1];
                O[s] = __builtin_amdgcn_mfma_f32_16x16x16f16(p, Vg[u], O[s], 0, 0, 0);
            }
        }
    }

    const size_t pobase = (size_t)(bh * 8 + ks) * 2048;
    #pragma unroll
    for (int s = 0; s < 4; ++s) {
        const int q16 = qbase + s * 16;
        #pragma unroll
        for (int j = 0; j < 4; ++j) {
            const int qq = q16 + quad * 4 + j;
            if (l15 < 12)       part_o[(pobase + qq) * 12 + l15] = f2b(O[s][j]);
            else if (l15 == 12) part_l[pobase + qq] = O[s][j];
        }
    }
}

// ---------------------------------------------------------------------------
// K3: MEGA — r7-exact structure ((256,3), x2 tile in LDS, 41.8 KB; measured
// 54.7 µs clean; r12 proved LDS bank conflicts are NOT on the critical path,
// so the swizzle is reverted). Round-13 single variable: combine loop gets
// #pragma unroll 4 — late blocks chained up to 8 dependent ~600cy segment
// loads; 4-deep static unroll co-issues 4 of them. In-flight window ~52
// values fits the (256,3) 170-reg budget with margin (r10's 57.8 entangled
// this with vb-packing; r9's spill was at the 128-reg (256,4) budget).
// ---------------------------------------------------------------------------
#define CIROWB 400
#define R2OFF  14400              // 36*400 : union { ct[48][72] | h-tile 34 rows }
#define X2OFF  28000              // R2OFF + 34*400
#define PSOFF  40288              // X2OFF + 32*192*2
__global__ __launch_bounds__(256, 3) void k_mega(
    const float* __restrict__ x, const bf16* __restrict__ part_o,
    const float* __restrict__ part_l, const bf16* __restrict__ wrepo,
    const float* __restrict__ bo, const float* __restrict__ g2,
    const float* __restrict__ lb2, const bf16* __restrict__ w1,
    const float* __restrict__ b1c, const bf16* __restrict__ w2,
    const float* __restrict__ b2c, float* __restrict__ outf)
{
    __shared__ __align__(16) char lds[41824];
    bf16* ct = (bf16*)(lds + R2OFF);          // [48][72] proj A-tile

    const int tid = threadIdx.x;
    const int wave = tid >> 6, lane = tid & 63;
    const int m16 = lane & 15, q = lane >> 4;
    const int rowbase = blockIdx.x * 32;
    const int b = rowbase >> 11, lrow = rowbase & 2047;
    const int colw = wave * 48;

    // ---- phase A0: combine partials for 36 halo rows (tile rows 0..35) ----
    if (tid < 144) {
        const int rr = tid >> 2, h = tid & 3;
        int qrow = lrow + rr - 2;
        qrow = qrow < 0 ? 0 : (qrow > 2047 ? 2047 : qrow);
        const int nsq = (qrow >> 8) + 1;       // segments valid for this row
        const size_t sb = (size_t)(b * 4 + h) * 8 * 2048 + qrow;
        float o[12];
        #pragma unroll
        for (int i = 0; i < 12; ++i) o[i] = 0.f;
        float l = 0.f;
        #pragma unroll 4
        for (int s = 0; s < 8; ++s) {          // static unroll-4: loads co-issue
            if (s < nsq) {
                l += part_l[sb + (size_t)s * 2048];
                const bf16x8 v8 = *(const bf16x8*)(part_o + (sb + (size_t)s * 2048) * 12);
                const bf16x4 v4 = *(const bf16x4*)(part_o + (sb + (size_t)s * 2048) * 12 + 8);
                #pragma unroll
                for (int i = 0; i < 8; ++i) o[i] += (float)v8[i];
                #pragma unroll
                for (int i = 0; i < 4; ++i) o[8 + i] += (float)v4[i];
            }
        }
        const float inv = 1.0f / l;
        bf16* ctp = ct + rr * 72 + h * 12;
        #pragma unroll
        for (int i = 0; i < 12; ++i) ctp[i] = f2b(o[i] * inv);
        bf16x4 z;
        #pragma unroll
        for (int i = 0; i < 4; ++i) z[i] = (__bf16)0.0f;
        *(bf16x4*)(ct + rr * 72 + 48 + h * 4) = z;   // zero K-pad cols 48..63
    } else {
        const int idx = tid - 144;             // zero ct rows 36..47
        if (idx < 108) {
            bf16x8 z;
            #pragma unroll
            for (int i = 0; i < 8; ++i) z[i] = (__bf16)0.0f;
            *(bf16x8*)(ct + 36 * 72 + idx * 8) = z;
        }
    }
    float bd1[3], bd2[3], gg2[3], bbl2[3], bod[3];
    #pragma unroll
    for (int j = 0; j < 3; ++j) {
        const int col = colw + j * 16 + m16;
        bd1[j] = b1c[col]; bd2[j] = b2c[col];
        gg2[j] = g2[col];  bbl2[j] = lb2[col]; bod[j] = bo[col];
    }
    __syncthreads();

    // ---- phase A1: proj MFMA, 3 M-tiles (48 rows, 36 live) x 3 N-tiles ----
    f32x4 pv[3][3];
    #pragma unroll
    for (int mt = 0; mt < 3; ++mt)
        #pragma unroll
        for (int j = 0; j < 3; ++j) pv[mt][j] = (f32x4){0.f, 0.f, 0.f, 0.f};
    #pragma unroll
    for (int kb = 0; kb < 2; ++kb) {
        bf16x8 a[3];
        #pragma unroll
        for (int mt = 0; mt < 3; ++mt)
            a[mt] = *(const bf16x8*)(ct + (mt * 16 + m16) * 72 + kb * 32 + q * 8);
        #pragma unroll
        for (int j = 0; j < 3; ++j) {
            const bf16x8 bb = *(const bf16x8*)(wrepo +
                ((size_t)kb * 192 + (size_t)(wave * 3 + j) * 16 + m16) * 32 + q * 8);
            #pragma unroll
            for (int mt = 0; mt < 3; ++mt)
                pv[mt][j] = __builtin_amdgcn_mfma_f32_16x16x32_bf16(a[mt], bb, pv[mt][j], 0, 0, 0);
        }
    }

    // ---- bias + residual x -> v; per-row sum/ssq (48-col partial per wave) ----
    #pragma unroll
    for (int mt = 0; mt < 3; ++mt) {
        const bool live = (mt < 2) || (q == 0);
        #pragma unroll
        for (int j = 0; j < 3; ++j) {
            const int col = colw + j * 16 + m16;
            #pragma unroll
            for (int reg = 0; reg < 4; ++reg) {
                int grow = lrow + mt * 16 + q * 4 + reg - 2;
                grow = grow < 0 ? 0 : (grow > 2047 ? 2047 : grow);
                float v = 0.f;
                if (live)
                    v = pv[mt][j][reg] + bod[j] + x[((size_t)b * 2048 + grow) * D_ + col];
                pv[mt][j][reg] = v;
            }
        }
    }
    {
        float* ps = (float*)(lds + PSOFF);     // [4][48][2]
        #pragma unroll
        for (int mt = 0; mt < 3; ++mt) {
            float sum[4], ssq[4];
            #pragma unroll
            for (int reg = 0; reg < 4; ++reg) {
                sum[reg] = pv[mt][0][reg] + pv[mt][1][reg] + pv[mt][2][reg];
                ssq[reg] = pv[mt][0][reg] * pv[mt][0][reg]
                         + pv[mt][1][reg] * pv[mt][1][reg]
                         + pv[mt][2][reg] * pv[mt][2][reg];
            }
            #pragma unroll
            for (int m = 1; m <= 8; m <<= 1) {
                #pragma unroll
                for (int reg = 0; reg < 4; ++reg) {
                    sum[reg] += __shfl_xor(sum[reg], m, 64);
                    ssq[reg] += __shfl_xor(ssq[reg], m, 64);
                }
            }
            if (m16 == 0) {
                #pragma unroll
                for (int reg = 0; reg < 4; ++reg) {
                    const int tr = mt * 16 + q * 4 + reg;
                    ps[(wave * 48 + tr) * 2 + 0] = sum[reg];
                    ps[(wave * 48 + tr) * 2 + 1] = ssq[reg];
                }
            }
        }
    }
    __syncthreads();

    // ---- LN2 stats; write xn2 -> conv-input tile, v -> x2 tile ----
    {
        const float* ps = (const float*)(lds + PSOFF);
        #pragma unroll
        for (int mt = 0; mt < 3; ++mt) {
            const bool live = (mt < 2) || (q == 0);
            float mean[4], rs[4];
            #pragma unroll
            for (int reg = 0; reg < 4; ++reg) {
                const int tr = mt * 16 + q * 4 + reg;
                float st = 0.f, sq = 0.f;
                #pragma unroll
                for (int w = 0; w < 4; ++w) {
                    st += ps[(w * 48 + tr) * 2 + 0];
                    sq += ps[(w * 48 + tr) * 2 + 1];
                }
                mean[reg] = st * (1.0f / 192.0f);
                const float var = sq * (1.0f / 192.0f) - mean[reg] * mean[reg];
                rs[reg] = rsqrtf(var + EPS_);
            }
            if (live) {
                #pragma unroll
                for (int j = 0; j < 3; ++j) {
                    const int col = colw + j * 16 + m16;
                    #pragma unroll
                    for (int reg = 0; reg < 4; ++reg) {
                        const int tr = mt * 16 + q * 4 + reg;
                        const float v = pv[mt][j][reg];
                        const float xn = (v - mean[reg]) * rs[reg] * gg2[j] + bbl2[j];
                        *(bf16*)(lds + tr * CIROWB + col * 2) = f2b(xn);
                        if (tr >= 2 && tr < 34)
                            *(bf16*)(lds + X2OFF + ((tr - 2) * 192 + col) * 2) = f2b(v);
                    }
                }
            }
        }
    }
    __syncthreads();

    // ---- phase B: conv1 (3 M-tiles, 34 valid h rows) ----
    const int laneA = m16 * CIROWB + q * 16;
    f32x4 acc1[3][3];
    #pragma unroll
    for (int mt = 0; mt < 3; ++mt)
        #pragma unroll
        for (int j = 0; j < 3; ++j) acc1[mt][j] = (f32x4){0.f, 0.f, 0.f, 0.f};

    #define LOADB(w, kb, j) \
        (*(const bf16x8*)((w) + ((size_t)(kb) * 192 + m16) * 32 + q * 8 \
                          + (size_t)(wave * 3 + (j)) * 16 * 32))
    {
        bf16x8 bB[2][3];
        #pragma unroll
        for (int j = 0; j < 3; ++j) bB[0][j] = LOADB(w1, 0, j);
        #pragma unroll
        for (int kb = 0; kb < 18; ++kb) {
            if (kb + 1 < 18) {
                #pragma unroll
                for (int j = 0; j < 3; ++j) bB[(kb + 1) & 1][j] = LOADB(w1, kb + 1, j);
            }
            const int t = kb / 6, c6 = kb % 6;
            bf16x8 a[3];
            #pragma unroll
            for (int mt = 0; mt < 3; ++mt)
                a[mt] = *(const bf16x8*)(lds + laneA + (mt * 16 + t) * CIROWB + c6 * 64);
            #pragma unroll
            for (int j = 0; j < 3; ++j)
                #pragma unroll
                for (int mt = 0; mt < 3; ++mt)
                    acc1[mt][j] = __builtin_amdgcn_mfma_f32_16x16x32_bf16(
                        a[mt], bB[kb & 1][j], acc1[mt][j], 0, 0, 0);
        }
    }

    // ---- h-tile (relu, edge-zero) -> LDS region2 rows 0..33 ----
    #pragma unroll
    for (int mt = 0; mt < 3; ++mt)
        #pragma unroll
        for (int j = 0; j < 3; ++j)
            #pragma unroll
            for (int reg = 0; reg < 4; ++reg) {
                const int hr = mt * 16 + q * 4 + reg;
                if (hr < 34) {
                    const int hm = lrow + hr - 1;
                    float v = fmaxf(acc1[mt][j][reg] + bd1[j], 0.f);
                    if (hm == 0 || hm == L_ - 1) v = 0.f;
                    *(bf16*)(lds + R2OFF + hr * CIROWB + (colw + j * 16 + m16) * 2) = f2b(v);
                }
            }
    __syncthreads();

    // ---- conv2: 2 M-tiles x 3 N-tiles, A from h-tile ----
    f32x4 acc2[2][3];
    #pragma unroll
    for (int mt = 0; mt < 2; ++mt)
        #pragma unroll
        for (int j = 0; j < 3; ++j) acc2[mt][j] = (f32x4){0.f, 0.f, 0.f, 0.f};
    {
        bf16x8 bB[2][3];
        #pragma unroll
        for (int j = 0; j < 3; ++j) bB[0][j] = LOADB(w2, 0, j);
        #pragma unroll
        for (int kb = 0; kb < 18; ++kb) {
            if (kb + 1 < 18) {
                #pragma unroll
                for (int j = 0; j < 3; ++j) bB[(kb + 1) & 1][j] = LOADB(w2, kb + 1, j);
            }
            const int t = kb / 6, c6 = kb % 6;
            bf16x8 a[2];
            #pragma unroll
            for (int mt = 0; mt < 2; ++mt)
                a[mt] = *(const bf16x8*)(lds + R2OFF + laneA + (mt * 16 + t) * CIROWB + c6 * 64);
            #pragma unroll
            for (int j = 0; j < 3; ++j)
                #pragma unroll
                for (int mt = 0; mt < 2; ++mt)
                    acc2[mt][j] = __builtin_amdgcn_mfma_f32_16x16x32_bf16(
                        a[mt], bB[kb & 1][j], acc2[mt][j], 0, 0, 0);
        }
    }
    #undef LOADB

    // ---- epilogue: residual (x+mha from x2 tile) + conv2 + store f32 ----
    #pragma unroll
    for (int j = 0; j < 3; ++j)
        #pragma unroll
        for (int mt = 0; mt < 2; ++mt)
            #pragma unroll
            for (int reg = 0; reg < 4; ++reg) {
                const int orr = mt * 16 + q * 4 + reg;
                const int r = rowbase + orr;
                const int m = r & (L_ - 1);
                const int col = colw + j * 16 + m16;
                float v = b2f(*(const bf16*)(lds + X2OFF + (orr * 192 + col) * 2));
                if (m != 0 && m != L_ - 1) v += acc2[mt][j][reg] + bd2[j];
                outf[(size_t)r * D_ + col] = v;
            }
}

// ---------------------------------------------------------------------------
extern "C" void kernel_launch(void* const* d_in, const int* in_sizes, int n_in,
                              void* d_out, int out_size, void* d_ws, size_t ws_size,
                              hipStream_t stream)
{
    const float* x    = (const float*)d_in[0];
    const float* ln1g = (const float*)d_in[1];
    const float* ln1b = (const float*)d_in[2];
    const float* wq   = (const float*)d_in[3];
    const float* bq   = (const float*)d_in[4];
    const float* wk   = (const float*)d_in[5];
    const float* bk   = (const float*)d_in[6];
    const float* wv   = (const float*)d_in[7];
    const float* bv   = (const float*)d_in[8];
    const float* wo   = (const float*)d_in[9];
    const float* bo   = (const float*)d_in[10];
    const float* ln2g = (const float*)d_in[11];
    const float* ln2b = (const float*)d_in[12];
    const float* c1w  = (const float*)d_in[13];
    const float* c1b  = (const float*)d_in[14];
    const float* c2w  = (const float*)d_in[15];
    const float* c2b  = (const float*)d_in[16];

    const size_t ROWS = (size_t)16 * L_;            // 32768
    char* ws = (char*)d_ws;
    size_t off = 0;
    f16* qb    = (f16*)(ws + off);   off += ROWS * HK_ * 2;  // 3.15 MB
    f16* kb    = (f16*)(ws + off);   off += ROWS * HK_ * 2;
    f16* vt    = (f16*)(ws + off);   off += (size_t)64 * 16 * 2048 * 2;   // 4.19 MB
    bf16* part_o = (bf16*)(ws + off); off += (size_t)64 * 8 * 2048 * 12 * 2; // 25.2 MB
    float* part_l = (float*)(ws + off); off += (size_t)64 * 8 * 2048 * 4;    //  4.2 MB
    bf16* wrep1 = (bf16*)(ws + off); off += 576 * 192 * 2;   // 221 KB
    bf16* wrep2 = (bf16*)(ws + off); off += 576 * 192 * 2;
    bf16* wrepq = (bf16*)(ws + off); off += 6 * 144 * 32 * 2;
    float* bias144 = (float*)(ws + off); off += 144 * 4;
    bf16* wrepo = (bf16*)(ws + off); off += 2 * 192 * 32 * 2; // total ~37 MB

    k_prep_all  <<<1021, 256, 0, stream>>>(c1w, c2w, wq, wk, wv, bq, bk, bv, wo,
                                           wrep1, wrep2, wrepq, bias144, wrepo);
    k_ln_qkv    <<<1024, 256, 0, stream>>>(x, ln1g, ln1b, wrepq, bias144, qb, kb, vt);
    k_attn_part <<<64 * 36, 256, 0, stream>>>(qb, kb, vt, part_o, part_l);
    k_mega      <<<1024, 256, 0, stream>>>(x, part_o, part_l, wrepo, bo, ln2g, ln2b,
                                           wrep1, c1b, wrep2, c2b, (float*)d_out);
}

// Round 14
// 192.923 us; speedup vs baseline: 1.0450x; 1.0008x over previous
//
#include <hip/hip_runtime.h>
#include <hip/hip_bf16.h>

#define L_ 2048
#define D_ 192
#define HK_ 48
#define EPS_ 1e-3f
#define SCALE_ 0.28867513459481287f  // 1/sqrt(12)
#define LOG2E_ 1.4426950408889634f

typedef __hip_bfloat16 bf16;
typedef _Float16 f16;
typedef __fp16 hf16x2 __attribute__((ext_vector_type(2)));   // builtin return type
typedef _Float16 f16x4 __attribute__((ext_vector_type(4)));
typedef __bf16 bf16x4 __attribute__((ext_vector_type(4)));
typedef __bf16 bf16x8 __attribute__((ext_vector_type(8)));
typedef float  f32x4  __attribute__((ext_vector_type(4)));

__device__ __forceinline__ float b2f(bf16 x) { return __bfloat162float(x); }
__device__ __forceinline__ bf16 f2b(float x) { return __float2bfloat16(x); }

// ---------------------------------------------------------------------------
// K0: single prep kernel — all weight repacks in one launch (unchanged).
// ---------------------------------------------------------------------------
__global__ __launch_bounds__(256) void k_prep_all(
    const float* __restrict__ c1w, const float* __restrict__ c2w,
    const float* __restrict__ wq, const float* __restrict__ wk, const float* __restrict__ wv,
    const float* __restrict__ bq, const float* __restrict__ bk, const float* __restrict__ bv,
    const float* __restrict__ wo,
    bf16* __restrict__ wrep1, bf16* __restrict__ wrep2,
    bf16* __restrict__ wrepq, float* __restrict__ bias144, bf16* __restrict__ wrepo)
{
    const int i = blockIdx.x * 256 + threadIdx.x;
    if (i < 110592) {
        const int k = i / 192, n = i - k * 192;
        wrep1[((size_t)(k >> 5) * 192 + n) * 32 + (k & 31)] = f2b(c1w[i]);
    } else if (i < 221184) {
        const int j = i - 110592;
        const int k = j / 192, n = j - k * 192;
        wrep2[((size_t)(k >> 5) * 192 + n) * 32 + (k & 31)] = f2b(c2w[j]);
    } else if (i < 248832) {
        const int j = i - 221184;
        const int kb = j / 4608, rem = j % 4608;
        const int n = rem / 32, kk = rem % 32;
        const int k = kb * 32 + kk;
        float v;
        if (n < 48)       v = wq[k * HK_ + n] * (SCALE_ * LOG2E_);
        else if (n < 96)  v = wk[k * HK_ + (n - 48)];
        else              v = wv[k * HK_ + (n - 96)];
        wrepq[j] = f2b(v);
    } else if (i < 248976) {
        const int j = i - 248832;
        bias144[j] = (j < 48) ? bq[j] * (SCALE_ * LOG2E_)
                   : (j < 96) ? bk[j - 48] : bv[j - 96];
    } else if (i < 261264) {
        const int j = i - 248976;
        const int kb = j / 6144, rem = j % 6144;
        const int n = rem / 32, kk = rem % 32;
        const int k = kb * 32 + kk;
        wrepo[j] = f2b(k < 48 ? wo[k * D_ + n] : 0.f);
    }
}

// ---------------------------------------------------------------------------
// K1: fused LN1 + QKV projection via MFMA (r7-exact; q/k head-contiguous
// [b*4+h][2048][12]).
// ---------------------------------------------------------------------------
__global__ __launch_bounds__(256, 4) void k_ln_qkv(
    const float* __restrict__ x, const float* __restrict__ g1, const float* __restrict__ b1,
    const bf16* __restrict__ wrep, const float* __restrict__ bias144,
    f16* __restrict__ qo, f16* __restrict__ ko, f16* __restrict__ vt)
{
    __shared__ bf16 xn[32 * 200];
    const int tid = threadIdx.x;
    const int wave = tid >> 6, lane = tid & 63;
    const int rowbase = blockIdx.x * 32;
    const int b = rowbase >> 11;
    const int lrow0 = rowbase & 2047;

    const float gg0 = g1[lane], gg1 = g1[lane + 64], gg2 = g1[lane + 128];
    const float bb0 = b1[lane], bb1 = b1[lane + 64], bb2 = b1[lane + 128];
    for (int i = 0; i < 8; ++i) {
        const int r = wave * 8 + i;
        const float* xp = x + (size_t)(rowbase + r) * D_;
        const float x0 = xp[lane];
        const float x1 = xp[lane + 64];
        const float x2 = xp[lane + 128];
        float s = x0 + x1 + x2;
        float q = x0 * x0 + x1 * x1 + x2 * x2;
        #pragma unroll
        for (int m = 1; m < 64; m <<= 1) {
            s += __shfl_xor(s, m, 64);
            q += __shfl_xor(q, m, 64);
        }
        const float mean = s * (1.0f / 192.0f);
        const float var  = q * (1.0f / 192.0f) - mean * mean;
        const float rs   = rsqrtf(var + EPS_);
        xn[r * 200 + lane]       = f2b((x0 - mean) * rs * gg0 + bb0);
        xn[r * 200 + lane + 64]  = f2b((x1 - mean) * rs * gg1 + bb1);
        xn[r * 200 + lane + 128] = f2b((x2 - mean) * rs * gg2 + bb2);
    }

    if (tid < 128) {
        const int h  = tid >> 5;
        const int vc = 12 + ((tid >> 3) & 3);
        const int p0 = lrow0 + (tid & 7) * 4;
        f16x4 vv;
        vv[0] = vv[1] = vv[2] = vv[3] = (vc == 12) ? (f16)1.0f : (f16)0.0f;
        *(f16x4*)(vt + ((size_t)(b * 4 + h) * 16 + vc) * 2048 + p0) = vv;
    }
    __syncthreads();

    const int l15 = lane & 15, q4 = lane >> 4;
    const int rt = wave >> 1, g = wave & 1;
    const int ntlim = 5 - g;                 // g=0: nt 0..4, g=1: nt 0..3 (+5)
    f32x4 acc[5];
    #pragma unroll
    for (int nt = 0; nt < 5; ++nt) acc[nt] = (f32x4){0.f, 0.f, 0.f, 0.f};

    const bf16* xrow = xn + (rt * 16 + l15) * 200 + q4 * 8;
    #pragma unroll
    for (int kb = 0; kb < 6; ++kb) {
        const bf16x8 a = *(const bf16x8*)(xrow + kb * 32);
        const bf16* wp = wrep + ((size_t)kb * 144 + l15) * 32 + q4 * 8
                       + (size_t)(g * 5) * 16 * 32;
        #pragma unroll
        for (int nt = 0; nt < 5; ++nt) {
            if (nt < ntlim) {
                const bf16x8 bfr = *(const bf16x8*)(wp + (size_t)nt * 16 * 32);
                acc[nt] = __builtin_amdgcn_mfma_f32_16x16x32_bf16(a, bfr, acc[nt], 0, 0, 0);
            }
        }
    }

    const int lr0 = lrow0 + rt * 16 + q4 * 4;
    #pragma unroll
    for (int nt = 0; nt < 5; ++nt) {
        if (nt < ntlim) {
            const int ntg = g * 5 + nt;
            const int col = ntg * 16 + l15;
            const float bd = bias144[col];
            if (ntg < 3) {
                const int h2 = col / 12, c12 = col - h2 * 12;
                #pragma unroll
                for (int reg = 0; reg < 4; ++reg)
                    qo[((size_t)(b * 4 + h2) * 2048 + lr0 + reg) * 12 + c12] =
                        (f16)(acc[nt][reg] + bd);
            } else if (ntg < 6) {
                const int ck = col - 48;
                const int h2 = ck / 12, c12 = ck - h2 * 12;
                #pragma unroll
                for (int reg = 0; reg < 4; ++reg)
                    ko[((size_t)(b * 4 + h2) * 2048 + lr0 + reg) * 12 + c12] =
                        (f16)(acc[nt][reg] + bd);
            } else {
                const int vcol = col - 96;
                const int h = vcol / 12, c12 = vcol % 12;
                f16x4 vv;
                #pragma unroll
                for (int reg = 0; reg < 4; ++reg) vv[reg] = (f16)(acc[nt][reg] + bd);
                *(f16x4*)(vt + ((size_t)(b * 4 + h) * 16 + c12) * 2048 +
                          lrow0 + rt * 16 + q4 * 4) = vv;
            }
        }
    }
}

// ---------------------------------------------------------------------------
// K2: split-k partials attention. Round-14 change: the k-loop had a RUNTIME
// trip count (ktmax), blocking cross-iteration software pipelining — each
// group's 8 loads waited behind the previous group's compute. 28/36 blocks
// are non-diagonal with ktmax = 16 constant: block-uniform branch gives them
// a fully static #pragma unroll loop (compiler overlaps group g+1 loads with
// group g compute). Diagonal blocks (short, 8/36) keep the dynamic loop.
// Loop BODY is textually identical via macro — no restructure (r10 lesson).
// ---------------------------------------------------------------------------
__global__ __launch_bounds__(256, 8) void k_attn_part(
    const f16* __restrict__ qh, const f16* __restrict__ kh, const f16* __restrict__ vt,
    bf16* __restrict__ part_o, float* __restrict__ part_l)
{
    const int tid = threadIdx.x;
    const int wv = tid >> 6, lane = tid & 63;
    const int quad = lane >> 4, l15 = lane & 15;
    const int bh = blockIdx.x / 36;
    int r = blockIdx.x % 36;
    int qt = 0;
    while (r >= qt + 1) { r -= qt + 1; ++qt; }
    const int ks = r;
    const size_t base  = (size_t)bh * 2048 * 12;          // head-contiguous
    const size_t vbase = ((size_t)bh * 16 + l15) * 2048;
    const int kbase = ks * 256;
    const int qbase = qt * 256 + wv * 64;
    const bool diag = (ks == qt);
    const int ktmax = diag ? 4 * (wv + 1) : 16;

    f16x4 Qf[4];
    #pragma unroll
    for (int s = 0; s < 4; ++s) {
        f16x4 v;
        if (quad < 3)
            v = *(const f16x4*)(qh + base + (size_t)(qbase + s * 16 + l15) * 12 + quad * 4);
        else { v[0] = (f16)LOG2E_; v[1] = 0; v[2] = 0; v[3] = 0; }   // hd12 = log2e
        Qf[s] = v;
    }

    f32x4 O[4];
    #pragma unroll
    for (int s = 0; s < 4; ++s) O[s] = (f32x4){0.f, 0.f, 0.f, 0.f};

#define ATTN_GROUP(GG, DIAG_FLAG)                                              \
    {                                                                          \
        f16x4 Kg[2], Vg[2];                                                    \
        _Pragma("unroll")                                                      \
        for (int u = 0; u < 2; ++u) {                                          \
            const int kt = (GG) + u;                                           \
            f16x4 kf;                                                          \
            if (quad < 3)                                                      \
                kf = *(const f16x4*)(kh + base +                               \
                     (size_t)(kbase + kt * 16 + l15) * 12 + quad * 4);         \
            else { kf[0] = (f16)-6.0f; kf[1] = 0; kf[2] = 0; kf[3] = 0; }      \
            Kg[u] = kf;                                                        \
            Vg[u] = *(const f16x4*)(vt + vbase + kbase + kt * 16 + quad * 4);  \
        }                                                                      \
        _Pragma("unroll")                                                      \
        for (int u = 0; u < 2; ++u) {                                          \
            const int k0 = kbase + ((GG) + u) * 16 + quad * 4;                 \
            _Pragma("unroll")                                                  \
            for (int s = 0; s < 4; ++s) {                                      \
                f32x4 sc = (f32x4){0.f, 0.f, 0.f, 0.f};                        \
                sc = __builtin_amdgcn_mfma_f32_16x16x16f16(Kg[u], Qf[s], sc, 0, 0, 0); \
                float p0 = __builtin_amdgcn_exp2f(sc[0]);                      \
                float p1 = __builtin_amdgcn_exp2f(sc[1]);                      \
                float p2 = __builtin_amdgcn_exp2f(sc[2]);                      \
                float p3 = __builtin_amdgcn_exp2f(sc[3]);                      \
                if (DIAG_FLAG) {                                               \
                    const int qg = qbase + s * 16 + l15;                       \
                    p0 = (k0 + 0 <= qg) ? p0 : 0.f;                            \
                    p1 = (k0 + 1 <= qg) ? p1 : 0.f;                            \
                    p2 = (k0 + 2 <= qg) ? p2 : 0.f;                            \
                    p3 = (k0 + 3 <= qg) ? p3 : 0.f;                            \
                }                                                              \
                const hf16x2 lo = __builtin_amdgcn_cvt_pkrtz(p0, p1);          \
                const hf16x2 hi = __builtin_amdgcn_cvt_pkrtz(p2, p3);          \
                f16x4 p;                                                       \
                p[0] = (f16)lo[0]; p[1] = (f16)lo[1];                          \
                p[2] = (f16)hi[0]; p[3] = (f16)hi[1];                          \
                O[s] = __builtin_amdgcn_mfma_f32_16x16x16f16(p, Vg[u], O[s], 0, 0, 0); \
            }                                                                  \
        }                                                                      \
    }

    if (!diag) {
        #pragma unroll
        for (int g = 0; g < 16; g += 2)
            ATTN_GROUP(g, false)
    } else {
        for (int g = 0; g < ktmax; g += 2)
            ATTN_GROUP(g, true)
    }
#undef ATTN_GROUP

    const size_t pobase = (size_t)(bh * 8 + ks) * 2048;
    #pragma unroll
    for (int s = 0; s < 4; ++s) {
        const int q16 = qbase + s * 16;
        #pragma unroll
        for (int j = 0; j < 4; ++j) {
            const int qq = q16 + quad * 4 + j;
            if (l15 < 12)       part_o[(pobase + qq) * 12 + l15] = f2b(O[s][j]);
            else if (l15 == 12) part_l[pobase + qq] = O[s][j];
        }
    }
}

// ---------------------------------------------------------------------------
// K3: MEGA — r13-exact (best measured: 53.6 µs, total 193.07).
// ---------------------------------------------------------------------------
#define CIROWB 400
#define R2OFF  14400              // 36*400 : union { ct[48][72] | h-tile 34 rows }
#define X2OFF  28000              // R2OFF + 34*400
#define PSOFF  40288              // X2OFF + 32*192*2
__global__ __launch_bounds__(256, 3) void k_mega(
    const float* __restrict__ x, const bf16* __restrict__ part_o,
    const float* __restrict__ part_l, const bf16* __restrict__ wrepo,
    const float* __restrict__ bo, const float* __restrict__ g2,
    const float* __restrict__ lb2, const bf16* __restrict__ w1,
    const float* __restrict__ b1c, const bf16* __restrict__ w2,
    const float* __restrict__ b2c, float* __restrict__ outf)
{
    __shared__ __align__(16) char lds[41824];
    bf16* ct = (bf16*)(lds + R2OFF);          // [48][72] proj A-tile

    const int tid = threadIdx.x;
    const int wave = tid >> 6, lane = tid & 63;
    const int m16 = lane & 15, q = lane >> 4;
    const int rowbase = blockIdx.x * 32;
    const int b = rowbase >> 11, lrow = rowbase & 2047;
    const int colw = wave * 48;

    // ---- phase A0: combine partials for 36 halo rows (tile rows 0..35) ----
    if (tid < 144) {
        const int rr = tid >> 2, h = tid & 3;
        int qrow = lrow + rr - 2;
        qrow = qrow < 0 ? 0 : (qrow > 2047 ? 2047 : qrow);
        const int nsq = (qrow >> 8) + 1;       // segments valid for this row
        const size_t sb = (size_t)(b * 4 + h) * 8 * 2048 + qrow;
        float o[12];
        #pragma unroll
        for (int i = 0; i < 12; ++i) o[i] = 0.f;
        float l = 0.f;
        #pragma unroll 4
        for (int s = 0; s < 8; ++s) {          // static unroll-4: loads co-issue
            if (s < nsq) {
                l += part_l[sb + (size_t)s * 2048];
                const bf16x8 v8 = *(const bf16x8*)(part_o + (sb + (size_t)s * 2048) * 12);
                const bf16x4 v4 = *(const bf16x4*)(part_o + (sb + (size_t)s * 2048) * 12 + 8);
                #pragma unroll
                for (int i = 0; i < 8; ++i) o[i] += (float)v8[i];
                #pragma unroll
                for (int i = 0; i < 4; ++i) o[8 + i] += (float)v4[i];
            }
        }
        const float inv = 1.0f / l;
        bf16* ctp = ct + rr * 72 + h * 12;
        #pragma unroll
        for (int i = 0; i < 12; ++i) ctp[i] = f2b(o[i] * inv);
        bf16x4 z;
        #pragma unroll
        for (int i = 0; i < 4; ++i) z[i] = (__bf16)0.0f;
        *(bf16x4*)(ct + rr * 72 + 48 + h * 4) = z;   // zero K-pad cols 48..63
    } else {
        const int idx = tid - 144;             // zero ct rows 36..47
        if (idx < 108) {
            bf16x8 z;
            #pragma unroll
            for (int i = 0; i < 8; ++i) z[i] = (__bf16)0.0f;
            *(bf16x8*)(ct + 36 * 72 + idx * 8) = z;
        }
    }
    float bd1[3], bd2[3], gg2[3], bbl2[3], bod[3];
    #pragma unroll
    for (int j = 0; j < 3; ++j) {
        const int col = colw + j * 16 + m16;
        bd1[j] = b1c[col]; bd2[j] = b2c[col];
        gg2[j] = g2[col];  bbl2[j] = lb2[col]; bod[j] = bo[col];
    }
    __syncthreads();

    // ---- phase A1: proj MFMA, 3 M-tiles (48 rows, 36 live) x 3 N-tiles ----
    f32x4 pv[3][3];
    #pragma unroll
    for (int mt = 0; mt < 3; ++mt)
        #pragma unroll
        for (int j = 0; j < 3; ++j) pv[mt][j] = (f32x4){0.f, 0.f, 0.f, 0.f};
    #pragma unroll
    for (int kb = 0; kb < 2; ++kb) {
        bf16x8 a[3];
        #pragma unroll
        for (int mt = 0; mt < 3; ++mt)
            a[mt] = *(const bf16x8*)(ct + (mt * 16 + m16) * 72 + kb * 32 + q * 8);
        #pragma unroll
        for (int j = 0; j < 3; ++j) {
            const bf16x8 bb = *(const bf16x8*)(wrepo +
                ((size_t)kb * 192 + (size_t)(wave * 3 + j) * 16 + m16) * 32 + q * 8);
            #pragma unroll
            for (int mt = 0; mt < 3; ++mt)
                pv[mt][j] = __builtin_amdgcn_mfma_f32_16x16x32_bf16(a[mt], bb, pv[mt][j], 0, 0, 0);
        }
    }

    // ---- bias + residual x -> v; per-row sum/ssq (48-col partial per wave) ----
    #pragma unroll
    for (int mt = 0; mt < 3; ++mt) {
        const bool live = (mt < 2) || (q == 0);
        #pragma unroll
        for (int j = 0; j < 3; ++j) {
            const int col = colw + j * 16 + m16;
            #pragma unroll
            for (int reg = 0; reg < 4; ++reg) {
                int grow = lrow + mt * 16 + q * 4 + reg - 2;
                grow = grow < 0 ? 0 : (grow > 2047 ? 2047 : grow);
                float v = 0.f;
                if (live)
                    v = pv[mt][j][reg] + bod[j] + x[((size_t)b * 2048 + grow) * D_ + col];
                pv[mt][j][reg] = v;
            }
        }
    }
    {
        float* ps = (float*)(lds + PSOFF);     // [4][48][2]
        #pragma unroll
        for (int mt = 0; mt < 3; ++mt) {
            float sum[4], ssq[4];
            #pragma unroll
            for (int reg = 0; reg < 4; ++reg) {
                sum[reg] = pv[mt][0][reg] + pv[mt][1][reg] + pv[mt][2][reg];
                ssq[reg] = pv[mt][0][reg] * pv[mt][0][reg]
                         + pv[mt][1][reg] * pv[mt][1][reg]
                         + pv[mt][2][reg] * pv[mt][2][reg];
            }
            #pragma unroll
            for (int m = 1; m <= 8; m <<= 1) {
                #pragma unroll
                for (int reg = 0; reg < 4; ++reg) {
                    sum[reg] += __shfl_xor(sum[reg], m, 64);
                    ssq[reg] += __shfl_xor(ssq[reg], m, 64);
                }
            }
            if (m16 == 0) {
                #pragma unroll
                for (int reg = 0; reg < 4; ++reg) {
                    const int tr = mt * 16 + q * 4 + reg;
                    ps[(wave * 48 + tr) * 2 + 0] = sum[reg];
                    ps[(wave * 48 + tr) * 2 + 1] = ssq[reg];
                }
            }
        }
    }
    __syncthreads();

    // ---- LN2 stats; write xn2 -> conv-input tile, v -> x2 tile ----
    {
        const float* ps = (const float*)(lds + PSOFF);
        #pragma unroll
        for (int mt = 0; mt < 3; ++mt) {
            const bool live = (mt < 2) || (q == 0);
            float mean[4], rs[4];
            #pragma unroll
            for (int reg = 0; reg < 4; ++reg) {
                const int tr = mt * 16 + q * 4 + reg;
                float st = 0.f, sq = 0.f;
                #pragma unroll
                for (int w = 0; w < 4; ++w) {
                    st += ps[(w * 48 + tr) * 2 + 0];
                    sq += ps[(w * 48 + tr) * 2 + 1];
                }
                mean[reg] = st * (1.0f / 192.0f);
                const float var = sq * (1.0f / 192.0f) - mean[reg] * mean[reg];
                rs[reg] = rsqrtf(var + EPS_);
            }
            if (live) {
                #pragma unroll
                for (int j = 0; j < 3; ++j) {
                    const int col = colw + j * 16 + m16;
                    #pragma unroll
                    for (int reg = 0; reg < 4; ++reg) {
                        const int tr = mt * 16 + q * 4 + reg;
                        const float v = pv[mt][j][reg];
                        const float xn = (v - mean[reg]) * rs[reg] * gg2[j] + bbl2[j];
                        *(bf16*)(lds + tr * CIROWB + col * 2) = f2b(xn);
                        if (tr >= 2 && tr < 34)
                            *(bf16*)(lds + X2OFF + ((tr - 2) * 192 + col) * 2) = f2b(v);
                    }
                }
            }
        }
    }
    __syncthreads();

    // ---- phase B: conv1 (3 M-tiles, 34 valid h rows) ----
    const int laneA = m16 * CIROWB + q * 16;
    f32x4 acc1[3][3];
    #pragma unroll
    for (int mt = 0; mt < 3; ++mt)
        #pragma unroll
        for (int j = 0; j < 3; ++j) acc1[mt][j] = (f32x4){0.f, 0.f, 0.f, 0.f};

    #define LOADB(w, kb, j) \
        (*(const bf16x8*)((w) + ((size_t)(kb) * 192 + m16) * 32 + q * 8 \
                          + (size_t)(wave * 3 + (j)) * 16 * 32))
    {
        bf16x8 bB[2][3];
        #pragma unroll
        for (int j = 0; j < 3; ++j) bB[0][j] = LOADB(w1, 0, j);
        #pragma unroll
        for (int kb = 0; kb < 18; ++kb) {
            if (kb + 1 < 18) {
                #pragma unroll
                for (int j = 0; j < 3; ++j) bB[(kb + 1) & 1][j] = LOADB(w1, kb + 1, j);
            }
            const int t = kb / 6, c6 = kb % 6;
            bf16x8 a[3];
            #pragma unroll
            for (int mt = 0; mt < 3; ++mt)
                a[mt] = *(const bf16x8*)(lds + laneA + (mt * 16 + t) * CIROWB + c6 * 64);
            #pragma unroll
            for (int j = 0; j < 3; ++j)
                #pragma unroll
                for (int mt = 0; mt < 3; ++mt)
                    acc1[mt][j] = __builtin_amdgcn_mfma_f32_16x16x32_bf16(
                        a[mt], bB[kb & 1][j], acc1[mt][j], 0, 0, 0);
        }
    }

    // ---- h-tile (relu, edge-zero) -> LDS region2 rows 0..33 ----
    #pragma unroll
    for (int mt = 0; mt < 3; ++mt)
        #pragma unroll
        for (int j = 0; j < 3; ++j)
            #pragma unroll
            for (int reg = 0; reg < 4; ++reg) {
                const int hr = mt * 16 + q * 4 + reg;
                if (hr < 34) {
                    const int hm = lrow + hr - 1;
                    float v = fmaxf(acc1[mt][j][reg] + bd1[j], 0.f);
                    if (hm == 0 || hm == L_ - 1) v = 0.f;
                    *(bf16*)(lds + R2OFF + hr * CIROWB + (colw + j * 16 + m16) * 2) = f2b(v);
                }
            }
    __syncthreads();

    // ---- conv2: 2 M-tiles x 3 N-tiles, A from h-tile ----
    f32x4 acc2[2][3];
    #pragma unroll
    for (int mt = 0; mt < 2; ++mt)
        #pragma unroll
        for (int j = 0; j < 3; ++j) acc2[mt][j] = (f32x4){0.f, 0.f, 0.f, 0.f};
    {
        bf16x8 bB[2][3];
        #pragma unroll
        for (int j = 0; j < 3; ++j) bB[0][j] = LOADB(w2, 0, j);
        #pragma unroll
        for (int kb = 0; kb < 18; ++kb) {
            if (kb + 1 < 18) {
                #pragma unroll
                for (int j = 0; j < 3; ++j) bB[(kb + 1) & 1][j] = LOADB(w2, kb + 1, j);
            }
            const int t = kb / 6, c6 = kb % 6;
            bf16x8 a[2];
            #pragma unroll
            for (int mt = 0; mt < 2; ++mt)
                a[mt] = *(const bf16x8*)(lds + R2OFF + laneA + (mt * 16 + t) * CIROWB + c6 * 64);
            #pragma unroll
            for (int j = 0; j < 3; ++j)
                #pragma unroll
                for (int mt = 0; mt < 2; ++mt)
                    acc2[mt][j] = __builtin_amdgcn_mfma_f32_16x16x32_bf16(
                        a[mt], bB[kb & 1][j], acc2[mt][j], 0, 0, 0);
        }
    }
    #undef LOADB

    // ---- epilogue: residual (x+mha from x2 tile) + conv2 + store f32 ----
    #pragma unroll
    for (int j = 0; j < 3; ++j)
        #pragma unroll
        for (int mt = 0; mt < 2; ++mt)
            #pragma unroll
            for (int reg = 0; reg < 4; ++reg) {
                const int orr = mt * 16 + q * 4 + reg;
                const int r = rowbase + orr;
                const int m = r & (L_ - 1);
                const int col = colw + j * 16 + m16;
                float v = b2f(*(const bf16*)(lds + X2OFF + (orr * 192 + col) * 2));
                if (m != 0 && m != L_ - 1) v += acc2[mt][j][reg] + bd2[j];
                outf[(size_t)r * D_ + col] = v;
            }
}

// ---------------------------------------------------------------------------
extern "C" void kernel_launch(void* const* d_in, const int* in_sizes, int n_in,
                              void* d_out, int out_size, void* d_ws, size_t ws_size,
                              hipStream_t stream)
{
    const float* x    = (const float*)d_in[0];
    const float* ln1g = (const float*)d_in[1];
    const float* ln1b = (const float*)d_in[2];
    const float* wq   = (const float*)d_in[3];
    const float* bq   = (const float*)d_in[4];
    const float* wk   = (const float*)d_in[5];
    const float* bk   = (const float*)d_in[6];
    const float* wv   = (const float*)d_in[7];
    const float* bv   = (const float*)d_in[8];
    const float* wo   = (const float*)d_in[9];
    const float* bo   = (const float*)d_in[10];
    const float* ln2g = (const float*)d_in[11];
    const float* ln2b = (const float*)d_in[12];
    const float* c1w  = (const float*)d_in[13];
    const float* c1b  = (const float*)d_in[14];
    const float* c2w  = (const float*)d_in[15];
    const float* c2b  = (const float*)d_in[16];

    const size_t ROWS = (size_t)16 * L_;            // 32768
    char* ws = (char*)d_ws;
    size_t off = 0;
    f16* qb    = (f16*)(ws + off);   off += ROWS * HK_ * 2;  // 3.15 MB
    f16* kb    = (f16*)(ws + off);   off += ROWS * HK_ * 2;
    f16* vt    = (f16*)(ws + off);   off += (size_t)64 * 16 * 2048 * 2;   // 4.19 MB
    bf16* part_o = (bf16*)(ws + off); off += (size_t)64 * 8 * 2048 * 12 * 2; // 25.2 MB
    float* part_l = (float*)(ws + off); off += (size_t)64 * 8 * 2048 * 4;    //  4.2 MB
    bf16* wrep1 = (bf16*)(ws + off); off += 576 * 192 * 2;   // 221 KB
    bf16* wrep2 = (bf16*)(ws + off); off += 576 * 192 * 2;
    bf16* wrepq = (bf16*)(ws + off); off += 6 * 144 * 32 * 2;
    float* bias144 = (float*)(ws + off); off += 144 * 4;
    bf16* wrepo = (bf16*)(ws + off); off += 2 * 192 * 32 * 2; // total ~37 MB

    k_prep_all  <<<1021, 256, 0, stream>>>(c1w, c2w, wq, wk, wv, bq, bk, bv, wo,
                                           wrep1, wrep2, wrepq, bias144, wrepo);
    k_ln_qkv    <<<1024, 256, 0, stream>>>(x, ln1g, ln1b, wrepq, bias144, qb, kb, vt);
    k_attn_part <<<64 * 36, 256, 0, stream>>>(qb, kb, vt, part_o, part_l);
    k_mega      <<<1024, 256, 0, stream>>>(x, part_o, part_l, wrepo, bo, ln2g, ln2b,
                                           wrep1, c1b, wrep2, c2b, (float*)d_out);
}